// Round 1
// baseline (494.855 us; speedup 1.0000x reference)
//
#include <hip/hip_runtime.h>
#include <math.h>

#define NN 4096
#define DD 256
#define DFF 512
#define HH 8
#define DHH 64

__device__ __forceinline__ float gelu_f(float x) {
    const float c = 0.7978845608028654f;
    float t = tanhf(c * (x + 0.044715f * x * x * x));
    return 0.5f * x * (1.0f + t);
}

// ---------------------------------------------------------------------------
// Tiled fp32 GEMM: C[M x NC] = A[M x K] @ B[K x NC] + bias, optional gelu.
// 64x64 tile per block, 256 threads, 4x4 per thread. A staged transposed in
// LDS (Ast[k][row], pad 68 keeps b128 reads aligned + conflict-light).
// ROWBIAS: bias = rowtab[rowidx[row]*NC + col] (per-row table, e.g. proj_bias)
// else     bias = colbias[col].
// ---------------------------------------------------------------------------
template<int GELU, int ROWBIAS>
__global__ __launch_bounds__(256) void gemm_kernel(
    const float* __restrict__ A, const float* __restrict__ B,
    const float* __restrict__ colbias,
    const float* __restrict__ rowtab, const int* __restrict__ rowidx,
    float* __restrict__ C, int K, int NC)
{
    __shared__ float Ast[16][68];
    __shared__ float Bs[16][64];
    const int tid = threadIdx.x;
    const int ty = tid >> 4, tx = tid & 15;
    const int row0 = blockIdx.y * 64, col0 = blockIdx.x * 64;
    const int lr = tid >> 2, lq = tid & 3;   // A loader: row, k-quad
    const int br = tid >> 4, bc = tid & 15;  // B loader: k-row, col-quad

    float acc[4][4] = {};

    for (int kk = 0; kk < K; kk += 16) {
        float4 a4 = *(const float4*)(A + (size_t)(row0 + lr) * K + kk + lq * 4);
        Ast[lq * 4 + 0][lr] = a4.x;
        Ast[lq * 4 + 1][lr] = a4.y;
        Ast[lq * 4 + 2][lr] = a4.z;
        Ast[lq * 4 + 3][lr] = a4.w;
        *(float4*)&Bs[br][bc * 4] =
            *(const float4*)(B + (size_t)(kk + br) * NC + col0 + bc * 4);
        __syncthreads();
#pragma unroll
        for (int k = 0; k < 16; ++k) {
            float4 av = *(const float4*)&Ast[k][ty * 4];
            float4 bv = *(const float4*)&Bs[k][tx * 4];
            float aa[4] = {av.x, av.y, av.z, av.w};
            float bb[4] = {bv.x, bv.y, bv.z, bv.w};
#pragma unroll
            for (int i = 0; i < 4; ++i)
#pragma unroll
                for (int j = 0; j < 4; ++j)
                    acc[i][j] += aa[i] * bb[j];
        }
        __syncthreads();
    }

#pragma unroll
    for (int i = 0; i < 4; ++i) {
        int row = row0 + ty * 4 + i;
        float4 bv;
        if (ROWBIAS)
            bv = *(const float4*)(rowtab + (size_t)rowidx[row] * NC + col0 + tx * 4);
        else
            bv = *(const float4*)(colbias + col0 + tx * 4);
        float o0 = acc[i][0] + bv.x;
        float o1 = acc[i][1] + bv.y;
        float o2 = acc[i][2] + bv.z;
        float o3 = acc[i][3] + bv.w;
        if (GELU) { o0 = gelu_f(o0); o1 = gelu_f(o1); o2 = gelu_f(o2); o3 = gelu_f(o3); }
        *(float4*)(C + (size_t)row * NC + col0 + tx * 4) = make_float4(o0, o1, o2, o3);
    }
}

// ---------------------------------------------------------------------------
// Segment outer-product MEAN, stored transposed:
//   ST[seg][h][b][a] = (1/max(cnt,1e-6)) * sum_{n: idx[n]==seg, mask[n]} k[n,h,a]*v[n,h,b]
// One block per (seg, h). Compacts matching n into LDS list, rank-8 updates.
// ---------------------------------------------------------------------------
__global__ __launch_bounds__(256) void seg_outer_kernel(
    const float* __restrict__ Kmat, const float* __restrict__ Vmat,
    const int* __restrict__ idx, const int* __restrict__ mask,
    float* __restrict__ ST)
{
    const int seg = blockIdx.x, h = blockIdx.y;
    __shared__ float Ks[8][64];
    __shared__ float Vs[8][64];
    __shared__ int list[256];
    __shared__ int cnt;
    const int tid = threadIdx.x;
    const int ty = tid >> 4, tx = tid & 15;
    const int mm = tid >> 6, kc = tid & 63;

    float acc[4][4] = {};
    int tot = 0;

    for (int base = 0; base < NN; base += 256) {
        int n = base + tid;
        if (tid == 0) cnt = 0;
        __syncthreads();
        if (idx[n] == seg && mask[n] != 0) {
            int p = atomicAdd(&cnt, 1);
            list[p] = n;
        }
        __syncthreads();
        int c = cnt;
        tot += c;
        for (int g = 0; g < c; g += 8) {
            int m = min(8, c - g);
            if (mm < m) {
                int nn = list[g + mm];
                Ks[mm][kc] = Kmat[(size_t)nn * DFF + h * DHH + kc];
                Vs[mm][kc] = Vmat[(size_t)nn * DFF + h * DHH + kc];
            }
            if (mm + 4 < m) {
                int nn = list[g + mm + 4];
                Ks[mm + 4][kc] = Kmat[(size_t)nn * DFF + h * DHH + kc];
                Vs[mm + 4][kc] = Vmat[(size_t)nn * DFF + h * DHH + kc];
            }
            __syncthreads();
            for (int q = 0; q < m; ++q) {
                float4 kv = *(const float4*)&Ks[q][ty * 4];
                float4 vv = *(const float4*)&Vs[q][tx * 4];
                float ka[4] = {kv.x, kv.y, kv.z, kv.w};
                float vb[4] = {vv.x, vv.y, vv.z, vv.w};
#pragma unroll
                for (int i = 0; i < 4; ++i)
#pragma unroll
                    for (int j = 0; j < 4; ++j)
                        acc[i][j] += ka[i] * vb[j];
            }
            __syncthreads();
        }
    }

    float scale = 1.0f / fmaxf((float)tot, 1e-6f);
    float* outp = ST + (((size_t)seg * HH + h) << 12);
#pragma unroll
    for (int j = 0; j < 4; ++j) {
        float4 w = make_float4(acc[0][j] * scale, acc[1][j] * scale,
                               acc[2][j] * scale, acc[3][j] * scale);
        *(float4*)(outp + (size_t)(tx * 4 + j) * 64 + ty * 4) = w;
    }
}

// ---------------------------------------------------------------------------
// Bmean[b][col] = masked mean over {n: batch[n]==b} of Braw[n][col], col in
// blocks of 256. Grid (4 colchunks, 8 batches).
// ---------------------------------------------------------------------------
__global__ __launch_bounds__(256) void bias_mean_kernel(
    const float* __restrict__ Braw, const int* __restrict__ batch,
    const int* __restrict__ mask, float* __restrict__ Bmean)
{
    const int b = blockIdx.y;
    const int col = blockIdx.x * 256 + threadIdx.x;
    __shared__ int list[256];
    __shared__ int cnt;
    const int tid = threadIdx.x;

    float acc = 0.0f;
    int tot = 0;
    for (int base = 0; base < NN; base += 256) {
        int n = base + tid;
        if (tid == 0) cnt = 0;
        __syncthreads();
        if (batch[n] == b && mask[n] != 0) {
            int p = atomicAdd(&cnt, 1);
            list[p] = n;
        }
        __syncthreads();
        int c = cnt;
        tot += c;
        for (int g = 0; g < c; ++g)
            acc += Braw[(size_t)list[g] * 1024 + col];
        __syncthreads();
    }
    Bmean[(size_t)b * 1024 + col] = acc / fmaxf((float)tot, 1e-6f);
}

// proj[b][j] = sum_k Bmean[b][k] * Wout[k][j].  Grid(8), 256 threads.
__global__ __launch_bounds__(256) void proj_bias_kernel(
    const float* __restrict__ Bmean, const float* __restrict__ Wout,
    float* __restrict__ proj)
{
    const int b = blockIdx.x;
    const int j = threadIdx.x;
    __shared__ float bm[1024];
    for (int e = threadIdx.x; e < 1024; e += 256)
        bm[e] = Bmean[(size_t)b * 1024 + e];
    __syncthreads();
    float acc = 0.0f;
#pragma unroll 4
    for (int k = 0; k < 1024; ++k)
        acc += bm[k] * Wout[(size_t)k * 256 + j];
    proj[(size_t)b * 256 + j] = acc;
}

// ---------------------------------------------------------------------------
// attn[n, h*128 + outoff + a] = sum_b ST[idx[n]][h][b][a] * q[n,h,b]
// One block per (seg, h, n-chunk). S tile in LDS, 16 n per inner group,
// 4 outputs (a-quad) per thread.
// ---------------------------------------------------------------------------
__global__ __launch_bounds__(256) void attn_einsum_kernel(
    const float* __restrict__ ST, const float* __restrict__ Qmat,
    const int* __restrict__ idx, float* __restrict__ attn,
    int outoff, int chunk)
{
    const int seg = blockIdx.x, h = blockIdx.y;
    const int nbase = blockIdx.z * chunk;
    __shared__ float Sl[64][68];   // Sl[b][a]
    __shared__ float qs[16][68];
    __shared__ int list[256];
    __shared__ int cnt;
    const int tid = threadIdx.x;
    const int v4 = tid & 15, slot = tid >> 4;

    const float* Sg = ST + (((size_t)seg * HH + h) << 12);
    for (int e = tid; e < 4096; e += 256)
        Sl[e >> 6][e & 63] = Sg[e];

    for (int base = nbase; base < nbase + chunk; base += 256) {
        int n = base + tid;
        if (tid == 0) cnt = 0;
        __syncthreads();
        if (idx[n] == seg) {
            int p = atomicAdd(&cnt, 1);
            list[p] = n;
        }
        __syncthreads();
        int c = cnt;
        for (int g = 0; g < c; g += 16) {
            int nn = (g + slot < c) ? list[g + slot] : -1;
            if (nn >= 0) {
                float4 qv = *(const float4*)(Qmat + (size_t)nn * DFF + h * DHH + v4 * 4);
                *(float4*)&qs[slot][v4 * 4] = qv;
            }
            __syncthreads();
            if (nn >= 0) {
                float a0 = 0, a1 = 0, a2 = 0, a3 = 0;
#pragma unroll
                for (int b = 0; b < 64; ++b) {
                    float qb = qs[slot][b];
                    float4 s = *(const float4*)&Sl[b][v4 * 4];
                    a0 += s.x * qb;
                    a1 += s.y * qb;
                    a2 += s.z * qb;
                    a3 += s.w * qb;
                }
                *(float4*)(attn + (size_t)nn * 1024 + h * 128 + outoff + v4 * 4) =
                    make_float4(a0, a1, a2, a3);
            }
            __syncthreads();
        }
    }
}

extern "C" void kernel_launch(void* const* d_in, const int* in_sizes, int n_in,
                              void* d_out, int out_size, void* d_ws, size_t ws_size,
                              hipStream_t stream)
{
    const float* local   = (const float*)d_in[0];
    const int*   chain   = (const int*)d_in[1];
    const int*   batch   = (const int*)d_in[2];
    const int*   mask    = (const int*)d_in[3];
    const float* W_key   = (const float*)d_in[4];
    const float* b_key   = (const float*)d_in[5];
    const float* W_value = (const float*)d_in[6];
    const float* b_value = (const float*)d_in[7];
    const float* W_query = (const float*)d_in[8];
    const float* b_query = (const float*)d_in[9];
    const float* W_bias  = (const float*)d_in[10];
    const float* b_bias  = (const float*)d_in[11];
    const float* W_out   = (const float*)d_in[12];
    float* out = (float*)d_out;

    float* ws = (float*)d_ws;
    float* Kmat  = ws;                      // 4096*512  = 2,097,152
    float* Vmat  = Kmat + 2097152;          // 2,097,152
    float* Qmat  = Vmat + 2097152;          // 2,097,152
    float* Braw  = Qmat + 2097152;          // 4096*1024 = 4,194,304
    float* attn  = Braw;                    // aliases Braw (Braw dead by then)
    float* STc   = Braw + 4194304;          // 64*8*4096 = 2,097,152
    float* STb   = STc + 2097152;           // 8*8*4096  = 262,144
    float* Bmean = STb + 262144;            // 8192
    float* proj  = Bmean + 8192;            // 2048
    // total ~13.0M floats = 52 MB

    dim3 blk(256);

    // k = gelu(local@W_key + b_key), v = local@W_value + b_value,
    // q = gelu(local@W_query + b_query), Braw = local@W_bias + b_bias
    gemm_kernel<1, 0><<<dim3(8, 64), blk, 0, stream>>>(local, W_key, b_key, nullptr, nullptr, Kmat, 256, 512);
    gemm_kernel<0, 0><<<dim3(8, 64), blk, 0, stream>>>(local, W_value, b_value, nullptr, nullptr, Vmat, 256, 512);
    gemm_kernel<1, 0><<<dim3(8, 64), blk, 0, stream>>>(local, W_query, b_query, nullptr, nullptr, Qmat, 256, 512);
    gemm_kernel<0, 0><<<dim3(16, 64), blk, 0, stream>>>(local, W_bias, b_bias, nullptr, nullptr, Braw, 256, 1024);

    // segment outer-product means (transposed layout)
    seg_outer_kernel<<<dim3(64, 8), blk, 0, stream>>>(Kmat, Vmat, chain, mask, STc);
    seg_outer_kernel<<<dim3(8, 8), blk, 0, stream>>>(Kmat, Vmat, batch, mask, STb);

    // bias path: per-batch mean, then project through W_out once (8 rows)
    bias_mean_kernel<<<dim3(4, 8), blk, 0, stream>>>(Braw, batch, mask, Bmean);
    proj_bias_kernel<<<dim3(8), blk, 0, stream>>>(Bmean, W_out, proj);

    // einsum: chain half (cols 0..63), batch half (cols 64..127) of each head
    attn_einsum_kernel<<<dim3(64, 8, 1), blk, 0, stream>>>(STc, Qmat, chain, attn, 0, 4096);
    attn_einsum_kernel<<<dim3(8, 8, 8), blk, 0, stream>>>(STb, Qmat, batch, attn, 64, 512);

    // out = attn @ W_out + proj[batch[n]]
    gemm_kernel<0, 1><<<dim3(4, 64), blk, 0, stream>>>(attn, W_out, nullptr, proj, batch, out, 1024, 256);
}

// Round 2
// 336.941 us; speedup vs baseline: 1.4687x; 1.4687x over previous
//
#include <hip/hip_runtime.h>
#include <math.h>

#define NN 4096
#define DD 256
#define DFF 512
#define HH 8
#define DHH 64

#define CAP_C 256
#define CAP_B 1024

// ws layout (float offsets)
#define OFF_K     0
#define OFF_V     2097152
#define OFF_Q     4194304
#define OFF_ATTN  6291456
#define OFF_STC   10485760
#define OFF_STB   12582912   /* zeroed span starts here */
#define OFF_LSUM  12845056
#define OFF_BSUM  12847104
#define OFF_CNT   12855296   /* 256 ints */
#define OFF_LISTS 12855552
#define ZERO_BYTES ((OFF_LISTS - OFF_STB) * 4)

__device__ __forceinline__ float gelu_f(float x) {
    const float c = 0.7978845608028654f;
    float t = tanhf(c * (x + 0.044715f * x * x * x));
    return 0.5f * x * (1.0f + t);
}

// ---------------------------------------------------------------------------
// Build per-segment row lists (masked + all) with global atomics. Grid 16x256.
// ---------------------------------------------------------------------------
__global__ __launch_bounds__(256) void build_lists_kernel(
    const int* __restrict__ chain, const int* __restrict__ batch,
    const int* __restrict__ mask,
    int* __restrict__ cntc_m, int* __restrict__ cntc_all,
    int* __restrict__ cntb_m, int* __restrict__ cntb_all,
    int* __restrict__ listc_m, int* __restrict__ listc_all,
    int* __restrict__ listb_m, int* __restrict__ listb_all)
{
    int n = blockIdx.x * 256 + threadIdx.x;
    int c = chain[n], b = batch[n], m = mask[n];
    int p;
    p = atomicAdd(&cntc_all[c], 1); if (p < CAP_C) listc_all[c * CAP_C + p] = n;
    p = atomicAdd(&cntb_all[b], 1); if (p < CAP_B) listb_all[b * CAP_B + p] = n;
    if (m) {
        p = atomicAdd(&cntc_m[c], 1); if (p < CAP_C) listc_m[c * CAP_C + p] = n;
        p = atomicAdd(&cntb_m[b], 1); if (p < CAP_B) listb_m[b * CAP_B + p] = n;
    }
}

// ---------------------------------------------------------------------------
// Fused K/V/Q GEMM: sel = blockIdx.x>>3 picks weight matrix; gelu on K,Q.
// 64x64 tile, 256 threads, 4x4 per thread, A transposed in LDS.
// ---------------------------------------------------------------------------
__global__ __launch_bounds__(256) void gemm_qkv_kernel(
    const float* __restrict__ A,
    const float* __restrict__ Wk, const float* __restrict__ bk,
    const float* __restrict__ Wv, const float* __restrict__ bv,
    const float* __restrict__ Wq, const float* __restrict__ bq,
    float* __restrict__ base)
{
    const int sel = blockIdx.x >> 3;
    const float* B    = (sel == 0) ? Wk : (sel == 1) ? Wv : Wq;
    const float* bias = (sel == 0) ? bk : (sel == 1) ? bv : bq;
    const int do_gelu = (sel != 1);
    float* C = base + (size_t)sel * 2097152;

    __shared__ float Ast[16][68];
    __shared__ float Bs[16][64];
    const int tid = threadIdx.x;
    const int ty = tid >> 4, tx = tid & 15;
    const int row0 = blockIdx.y * 64, col0 = (blockIdx.x & 7) * 64;
    const int lr = tid >> 2, lq = tid & 3;
    const int br = tid >> 4, bc = tid & 15;

    float acc[4][4] = {};
    for (int kk = 0; kk < DD; kk += 16) {
        float4 a4 = *(const float4*)(A + (size_t)(row0 + lr) * DD + kk + lq * 4);
        Ast[lq * 4 + 0][lr] = a4.x;
        Ast[lq * 4 + 1][lr] = a4.y;
        Ast[lq * 4 + 2][lr] = a4.z;
        Ast[lq * 4 + 3][lr] = a4.w;
        *(float4*)&Bs[br][bc * 4] =
            *(const float4*)(B + (size_t)(kk + br) * DFF + col0 + bc * 4);
        __syncthreads();
#pragma unroll
        for (int k = 0; k < 16; ++k) {
            float4 av = *(const float4*)&Ast[k][ty * 4];
            float4 bv4 = *(const float4*)&Bs[k][tx * 4];
            float aa[4] = {av.x, av.y, av.z, av.w};
            float bb[4] = {bv4.x, bv4.y, bv4.z, bv4.w};
#pragma unroll
            for (int i = 0; i < 4; ++i)
#pragma unroll
                for (int j = 0; j < 4; ++j)
                    acc[i][j] += aa[i] * bb[j];
        }
        __syncthreads();
    }
    float4 bv4 = *(const float4*)(bias + col0 + tx * 4);
#pragma unroll
    for (int i = 0; i < 4; ++i) {
        int row = row0 + ty * 4 + i;
        float o0 = acc[i][0] + bv4.x;
        float o1 = acc[i][1] + bv4.y;
        float o2 = acc[i][2] + bv4.z;
        float o3 = acc[i][3] + bv4.w;
        if (do_gelu) { o0 = gelu_f(o0); o1 = gelu_f(o1); o2 = gelu_f(o2); o3 = gelu_f(o3); }
        *(float4*)(C + (size_t)row * DFF + col0 + tx * 4) = make_float4(o0, o1, o2, o3);
    }
}

// ---------------------------------------------------------------------------
// Plain GEMM (final): C[M x NC] = A[M x K] @ B[K x NC], no bias.
// ---------------------------------------------------------------------------
__global__ __launch_bounds__(256) void gemm_plain_kernel(
    const float* __restrict__ A, const float* __restrict__ B,
    float* __restrict__ C, int K, int NC)
{
    __shared__ float Ast[16][68];
    __shared__ float Bs[16][64];
    const int tid = threadIdx.x;
    const int ty = tid >> 4, tx = tid & 15;
    const int row0 = blockIdx.y * 64, col0 = blockIdx.x * 64;
    const int lr = tid >> 2, lq = tid & 3;
    const int br = tid >> 4, bc = tid & 15;

    float acc[4][4] = {};
    for (int kk = 0; kk < K; kk += 16) {
        float4 a4 = *(const float4*)(A + (size_t)(row0 + lr) * K + kk + lq * 4);
        Ast[lq * 4 + 0][lr] = a4.x;
        Ast[lq * 4 + 1][lr] = a4.y;
        Ast[lq * 4 + 2][lr] = a4.z;
        Ast[lq * 4 + 3][lr] = a4.w;
        *(float4*)&Bs[br][bc * 4] =
            *(const float4*)(B + (size_t)(kk + br) * NC + col0 + bc * 4);
        __syncthreads();
#pragma unroll
        for (int k = 0; k < 16; ++k) {
            float4 av = *(const float4*)&Ast[k][ty * 4];
            float4 bv4 = *(const float4*)&Bs[k][tx * 4];
            float aa[4] = {av.x, av.y, av.z, av.w};
            float bb[4] = {bv4.x, bv4.y, bv4.z, bv4.w};
#pragma unroll
            for (int i = 0; i < 4; ++i)
#pragma unroll
                for (int j = 0; j < 4; ++j)
                    acc[i][j] += aa[i] * bb[j];
        }
        __syncthreads();
    }
#pragma unroll
    for (int i = 0; i < 4; ++i) {
        int row = row0 + ty * 4 + i;
        *(float4*)(C + (size_t)row * NC + col0 + tx * 4) =
            make_float4(acc[i][0], acc[i][1], acc[i][2], acc[i][3]);
    }
}

// ---------------------------------------------------------------------------
// Lsum[seg][d] = sum over masked batch rows of local[n][d]. Grid (8 seg, 4 z).
// ---------------------------------------------------------------------------
__global__ __launch_bounds__(256) void lsum_kernel(
    const float* __restrict__ local, const int* __restrict__ listb_m,
    const int* __restrict__ cntb_m, float* __restrict__ Lsum)
{
    const int seg = blockIdx.x, z = blockIdx.y;
    const int tid = threadIdx.x;
    int c = min(cntb_m[seg], CAP_B);
    int chunk = (c + 3) / 4;
    int r0 = z * chunk, r1 = min(c, r0 + chunk);
    float acc = 0.0f;
    for (int g = r0; g < r1; ++g) {
        int n = listb_m[seg * CAP_B + g];
        acc += local[(size_t)n * DD + tid];
    }
    atomicAdd(&Lsum[seg * DD + tid], acc);
}

// ---------------------------------------------------------------------------
// Bsum[seg][j] = sum_k Lsum[seg][k] * W_bias[k][j]. Grid (8 seg, 8 ksplit).
// ---------------------------------------------------------------------------
__global__ __launch_bounds__(256) void bsum_kernel(
    const float* __restrict__ Lsum, const float* __restrict__ W_bias,
    float* __restrict__ Bsum)
{
    const int seg = blockIdx.x, kz = blockIdx.y;
    const int tid = threadIdx.x;
    float4 acc = make_float4(0, 0, 0, 0);
    for (int k = kz * 32; k < kz * 32 + 32; ++k) {
        float l = Lsum[seg * DD + k];
        float4 w = *(const float4*)(W_bias + (size_t)k * 1024 + tid * 4);
        acc.x += l * w.x; acc.y += l * w.y; acc.z += l * w.z; acc.w += l * w.w;
    }
    float* o = Bsum + (size_t)seg * 1024 + tid * 4;
    atomicAdd(o + 0, acc.x);
    atomicAdd(o + 1, acc.y);
    atomicAdd(o + 2, acc.z);
    atomicAdd(o + 3, acc.w);
}

// ---------------------------------------------------------------------------
// Segment outer-product SUM from a precomputed masked list.
//   ST[seg][h][b][a] += sum k[n,h,a] * v[n,h,b]
// Grid (nseg, 8 h, nz). nz==1 -> direct store; else atomicAdd into zeroed ST.
// ---------------------------------------------------------------------------
__global__ __launch_bounds__(256) void seg_outer_list_kernel(
    const float* __restrict__ Kmat, const float* __restrict__ Vmat,
    const int* __restrict__ list, const int* __restrict__ cnts, int cap,
    float* __restrict__ ST, int nz)
{
    const int seg = blockIdx.x, h = blockIdx.y, z = blockIdx.z;
    __shared__ float Ks[8][64];
    __shared__ float Vs[8][64];
    const int tid = threadIdx.x;
    const int ty = tid >> 4, tx = tid & 15;
    const int mm = tid >> 6, kc = tid & 63;

    int c = min(cnts[seg], cap);
    int chunk = (c + nz - 1) / nz;
    int r0 = z * chunk, r1 = min(c, r0 + chunk);

    float acc[4][4] = {};
    for (int g = r0; g < r1; g += 8) {
        int m = min(8, r1 - g);
        if (mm < m) {
            int nn = list[seg * cap + g + mm];
            Ks[mm][kc] = Kmat[(size_t)nn * DFF + h * DHH + kc];
            Vs[mm][kc] = Vmat[(size_t)nn * DFF + h * DHH + kc];
        }
        if (mm + 4 < m) {
            int nn = list[seg * cap + g + mm + 4];
            Ks[mm + 4][kc] = Kmat[(size_t)nn * DFF + h * DHH + kc];
            Vs[mm + 4][kc] = Vmat[(size_t)nn * DFF + h * DHH + kc];
        }
        __syncthreads();
        for (int q = 0; q < m; ++q) {
            float4 kv = *(const float4*)&Ks[q][ty * 4];
            float4 vv = *(const float4*)&Vs[q][tx * 4];
            float ka[4] = {kv.x, kv.y, kv.z, kv.w};
            float vb[4] = {vv.x, vv.y, vv.z, vv.w};
#pragma unroll
            for (int i = 0; i < 4; ++i)
#pragma unroll
                for (int j = 0; j < 4; ++j)
                    acc[i][j] += ka[i] * vb[j];
        }
        __syncthreads();
    }

    float* outp = ST + (((size_t)seg * HH + h) << 12);
    if (nz == 1) {
#pragma unroll
        for (int j = 0; j < 4; ++j) {
            *(float4*)(outp + (size_t)(tx * 4 + j) * 64 + ty * 4) =
                make_float4(acc[0][j], acc[1][j], acc[2][j], acc[3][j]);
        }
    } else {
#pragma unroll
        for (int j = 0; j < 4; ++j) {
            float* o = outp + (size_t)(tx * 4 + j) * 64 + ty * 4;
            atomicAdd(o + 0, acc[0][j]);
            atomicAdd(o + 1, acc[1][j]);
            atomicAdd(o + 2, acc[2][j]);
            atomicAdd(o + 3, acc[3][j]);
        }
    }
}

// ---------------------------------------------------------------------------
// Einsum from list + fused scale + fused bias:
//   attn[n, h*128+outoff+a] = sum_b ST[seg][h][b][a]*inv_m[seg] * q[n,h,b]
//                           + (Bsum[batch[n]][col] + cnt_b*b_bias[col]) * inv_b
// Grid (nseg, 8 h, nz).
// ---------------------------------------------------------------------------
__global__ __launch_bounds__(256) void attn_einsum_list_kernel(
    const float* __restrict__ ST, const int* __restrict__ cnt_m,
    const float* __restrict__ Qmat,
    const int* __restrict__ list_all, const int* __restrict__ cnt_all, int cap,
    const int* __restrict__ batch, const int* __restrict__ cntb_m,
    const float* __restrict__ Bsum, const float* __restrict__ b_bias,
    float* __restrict__ attn, int outoff, int nz)
{
    const int seg = blockIdx.x, h = blockIdx.y, z = blockIdx.z;
    __shared__ float Sl[64][68];
    __shared__ float qs[16][68];
    const int tid = threadIdx.x;
    const int v4 = tid & 15, slot = tid >> 4;

    float scaleS = 1.0f / fmaxf((float)cnt_m[seg], 1e-6f);
    const float* Sg = ST + (((size_t)seg * HH + h) << 12);
    for (int e = tid; e < 4096; e += 256)
        Sl[e >> 6][e & 63] = Sg[e] * scaleS;

    int c = min(cnt_all[seg], cap);
    int chunk = (c + nz - 1) / nz;
    int r0 = z * chunk, r1 = min(c, r0 + chunk);
    __syncthreads();

    for (int g = r0; g < r1; g += 16) {
        int nn = (g + slot < r1) ? list_all[seg * cap + g + slot] : -1;
        if (nn >= 0) {
            float4 qv = *(const float4*)(Qmat + (size_t)nn * DFF + h * DHH + v4 * 4);
            *(float4*)&qs[slot][v4 * 4] = qv;
        }
        __syncthreads();
        if (nn >= 0) {
            float a0 = 0, a1 = 0, a2 = 0, a3 = 0;
#pragma unroll
            for (int b = 0; b < 64; ++b) {
                float qb = qs[slot][b];
                float4 s = *(const float4*)&Sl[b][v4 * 4];
                a0 += s.x * qb;
                a1 += s.y * qb;
                a2 += s.z * qb;
                a3 += s.w * qb;
            }
            int col0 = h * 128 + outoff + v4 * 4;
            int bb = batch[nn];
            float cm = (float)cntb_m[bb];
            float inv = 1.0f / fmaxf(cm, 1e-6f);
            float4 bi = *(const float4*)(b_bias + col0);
            float4 bs = *(const float4*)(Bsum + (size_t)bb * 1024 + col0);
            a0 += (bs.x + cm * bi.x) * inv;
            a1 += (bs.y + cm * bi.y) * inv;
            a2 += (bs.z + cm * bi.z) * inv;
            a3 += (bs.w + cm * bi.w) * inv;
            *(float4*)(attn + (size_t)nn * 1024 + col0) = make_float4(a0, a1, a2, a3);
        }
        __syncthreads();
    }
}

extern "C" void kernel_launch(void* const* d_in, const int* in_sizes, int n_in,
                              void* d_out, int out_size, void* d_ws, size_t ws_size,
                              hipStream_t stream)
{
    const float* local   = (const float*)d_in[0];
    const int*   chain   = (const int*)d_in[1];
    const int*   batch   = (const int*)d_in[2];
    const int*   mask    = (const int*)d_in[3];
    const float* W_key   = (const float*)d_in[4];
    const float* b_key   = (const float*)d_in[5];
    const float* W_value = (const float*)d_in[6];
    const float* b_value = (const float*)d_in[7];
    const float* W_query = (const float*)d_in[8];
    const float* b_query = (const float*)d_in[9];
    const float* W_bias  = (const float*)d_in[10];
    const float* b_bias  = (const float*)d_in[11];
    const float* W_out   = (const float*)d_in[12];
    float* out = (float*)d_out;

    float* ws = (float*)d_ws;
    float* Kmat  = ws + OFF_K;
    float* Qmat  = ws + OFF_Q;
    float* attn  = ws + OFF_ATTN;
    float* STc   = ws + OFF_STC;
    float* STb   = ws + OFF_STB;
    float* Lsum  = ws + OFF_LSUM;
    float* Bsum  = ws + OFF_BSUM;
    int*   cnt   = (int*)(ws + OFF_CNT);
    int* cntc_m   = cnt + 0;
    int* cntc_all = cnt + 64;
    int* cntb_m   = cnt + 128;
    int* cntb_all = cnt + 136;
    int* lists    = (int*)(ws + OFF_LISTS);
    int* listc_m   = lists;
    int* listc_all = listc_m + 64 * CAP_C;
    int* listb_m   = listc_all + 64 * CAP_C;
    int* listb_all = listb_m + 8 * CAP_B;

    dim3 blk(256);

    // zero the accumulator + counter span
    hipMemsetAsync(ws + OFF_STB, 0, ZERO_BYTES, stream);

    // build segment row lists
    build_lists_kernel<<<dim3(16), blk, 0, stream>>>(
        chain, batch, mask, cntc_m, cntc_all, cntb_m, cntb_all,
        listc_m, listc_all, listb_m, listb_all);

    // K/V/Q = local @ {W_key,W_value,W_query} (+bias, gelu on K,Q)
    gemm_qkv_kernel<<<dim3(24, 64), blk, 0, stream>>>(
        local, W_key, b_key, W_value, b_value, W_query, b_query, Kmat);

    // bias path: masked row-sum of local, then micro-GEMM through W_bias
    lsum_kernel<<<dim3(8, 4), blk, 0, stream>>>(local, listb_m, cntb_m, Lsum);
    bsum_kernel<<<dim3(8, 8), blk, 0, stream>>>(Lsum, W_bias, Bsum);

    // segment outer-product sums
    seg_outer_list_kernel<<<dim3(64, 8, 1), blk, 0, stream>>>(
        Kmat, Kmat + 2097152, listc_m, cntc_m, CAP_C, STc, 1);
    seg_outer_list_kernel<<<dim3(8, 8, 8), blk, 0, stream>>>(
        Kmat, Kmat + 2097152, listb_m, cntb_m, CAP_B, STb, 8);

    // einsum (+scale, +bias): chain half then batch half
    attn_einsum_list_kernel<<<dim3(64, 8, 1), blk, 0, stream>>>(
        STc, cntc_m, Qmat, listc_all, cntc_all, CAP_C,
        batch, cntb_m, Bsum, b_bias, attn, 0, 1);
    attn_einsum_list_kernel<<<dim3(8, 8, 8), blk, 0, stream>>>(
        STb, cntb_m, Qmat, listb_all, cntb_all, CAP_B,
        batch, cntb_m, Bsum, b_bias, attn, 64, 8);

    // out = attn @ W_out
    gemm_plain_kernel<<<dim3(4, 64), blk, 0, stream>>>(attn, W_out, out, 1024, 256);
}

// Round 3
// 262.459 us; speedup vs baseline: 1.8855x; 1.2838x over previous
//
#include <hip/hip_runtime.h>
#include <math.h>

#define NN 4096
#define DD 256
#define DFF 512
#define HH 8
#define DHH 64

#define CAP_C 256
#define CAP_B 1024

// ws layout (float-element offsets)
#define OFF_K      0
#define OFF_V      2097152
#define OFF_Q      4194304
#define OFF_ATTNB  6291456   /* bf16 attn [4096][1024] = 2,097,152 floats */
#define OFF_STC    8388608
#define OFF_STB    10485760  /* zero span start */
#define OFF_LSUM   10747904
#define OFF_BSUM   10749952
#define OFF_CNT    10758144  /* 256 ints */
#define OFF_LOCALB 10758400  /* zero span end; bf16 local, 524288 floats */
#define OFF_WQKVT  11282688  /* bf16 Wqkv^T [1536][256], 196608 floats */
#define OFF_WOUTT  11479296  /* bf16 Wout^T [256][1024], 131072 floats */
#define OFF_LISTS  11610368  /* 49152 ints */
#define ZERO_BYTES ((OFF_LOCALB - OFF_STB) * 4)

typedef __attribute__((ext_vector_type(8))) short bf16x8;
typedef __attribute__((ext_vector_type(4))) float floatx4;

__device__ __forceinline__ float gelu_f(float x) {
    const float c = 0.7978845608028654f;
    float t = tanhf(c * (x + 0.044715f * x * x * x));
    return 0.5f * x * (1.0f + t);
}

__device__ __forceinline__ unsigned short f2b(float f) {
    union { float f; unsigned int u; } v; v.f = f;
    unsigned int r = (v.u + 0x7FFFu + ((v.u >> 16) & 1u)) >> 16;
    return (unsigned short)r;
}

// ---------------------------------------------------------------------------
// prep: [0,1024) cast local->bf16; [1024,1664) transpose-cast weights;
// [1664,1680) build segment lists.
// ---------------------------------------------------------------------------
__global__ __launch_bounds__(256) void prep_kernel(
    const float* __restrict__ local,
    const float* __restrict__ Wk, const float* __restrict__ Wv,
    const float* __restrict__ Wq, const float* __restrict__ Wout,
    unsigned short* __restrict__ localb, unsigned short* __restrict__ Wqkvt,
    unsigned short* __restrict__ Woutt,
    const int* __restrict__ chain, const int* __restrict__ batch,
    const int* __restrict__ mask,
    int* __restrict__ cntc_m, int* __restrict__ cntc_all,
    int* __restrict__ cntb_m, int* __restrict__ cntb_all,
    int* __restrict__ listc_m, int* __restrict__ listc_all,
    int* __restrict__ listb_m, int* __restrict__ listb_all)
{
    const int bid = blockIdx.x, tid = threadIdx.x;
    if (bid < 1024) {
        int base = bid * 1024 + tid * 4;
        float4 v = *(const float4*)(local + base);
        ushort4 o;
        o.x = f2b(v.x); o.y = f2b(v.y); o.z = f2b(v.z); o.w = f2b(v.w);
        *(ushort4*)(localb + base) = o;
    } else if (bid < 1664) {
        int t = bid - 1024;
        const float* src; unsigned short* dst; int R, C, r0, c0;
        if (t < 384) {
            int m = t >> 7, ti = t & 127;
            src = (m == 0) ? Wk : (m == 1) ? Wv : Wq;
            dst = Wqkvt + (size_t)m * 512 * 256;
            R = 256; C = 512;
            r0 = (ti >> 4) * 32; c0 = (ti & 15) * 32;
        } else {
            int ti = t - 384;
            src = Wout; dst = Woutt;
            R = 1024; C = 256;
            r0 = (ti >> 3) * 32; c0 = (ti & 7) * 32;
        }
        __shared__ float Tl[32][33];
        int ty = tid >> 3, tx = tid & 7;
        float4 v = *(const float4*)(src + (size_t)(r0 + ty) * C + c0 + tx * 4);
        Tl[tx * 4 + 0][ty] = v.x;
        Tl[tx * 4 + 1][ty] = v.y;
        Tl[tx * 4 + 2][ty] = v.z;
        Tl[tx * 4 + 3][ty] = v.w;
        __syncthreads();
        int cy = tid >> 3, rx = tid & 7;
        ushort4 o;
        o.x = f2b(Tl[cy][rx * 4 + 0]);
        o.y = f2b(Tl[cy][rx * 4 + 1]);
        o.z = f2b(Tl[cy][rx * 4 + 2]);
        o.w = f2b(Tl[cy][rx * 4 + 3]);
        *(ushort4*)(dst + (size_t)(c0 + cy) * R + r0 + rx * 4) = o;
    } else {
        int n = (bid - 1664) * 256 + tid;
        int c = chain[n], b = batch[n], m = mask[n];
        int p;
        p = atomicAdd(&cntc_all[c], 1); if (p < CAP_C) listc_all[c * CAP_C + p] = n;
        p = atomicAdd(&cntb_all[b], 1); if (p < CAP_B) listb_all[b * CAP_B + p] = n;
        if (m) {
            p = atomicAdd(&cntc_m[c], 1); if (p < CAP_C) listc_m[c * CAP_C + p] = n;
            p = atomicAdd(&cntb_m[b], 1); if (p < CAP_B) listb_m[b * CAP_B + p] = n;
        }
    }
}

// ---------------------------------------------------------------------------
// MFMA QKV GEMM: C_sel = [gelu](localb @ W_sel + b_sel), sel = col/512.
// 64x64 tile, BK=64, 4 waves x 4 col-tiles of 16x16x32 bf16 MFMA.
// A [4096][256] bf16 row-major; Bt [1536][256] bf16 (W^T). Out fp32.
// ---------------------------------------------------------------------------
__global__ __launch_bounds__(256) void mfma_gemm_qkv(
    const unsigned short* __restrict__ A, const unsigned short* __restrict__ Bt,
    const float* __restrict__ bk, const float* __restrict__ bv,
    const float* __restrict__ bq, float* __restrict__ Kbase)
{
    const int K = 256;
    __shared__ unsigned short Asl[64][72];
    __shared__ unsigned short Bsl[64][72];
    const int tid = threadIdx.x;
    const int wave = tid >> 6, lane = tid & 63;
    const int q = lane >> 4, r = lane & 15;
    const int row0 = blockIdx.y * 64, cg0 = blockIdx.x * 64;

    floatx4 acc[4] = {};
    for (int kk = 0; kk < K; kk += 64) {
#pragma unroll
        for (int i = 0; i < 2; ++i) {
            int lin = tid * 2 + i;
            int rr = lin >> 3, kc = (lin & 7) * 8;
            *(float4*)&Asl[rr][kc] = *(const float4*)(A + (size_t)(row0 + rr) * K + kk + kc);
            *(float4*)&Bsl[rr][kc] = *(const float4*)(Bt + (size_t)(cg0 + rr) * K + kk + kc);
        }
        __syncthreads();
#pragma unroll
        for (int sub = 0; sub < 2; ++sub) {
            bf16x8 a = *(const bf16x8*)&Asl[wave * 16 + r][sub * 32 + q * 8];
#pragma unroll
            for (int c = 0; c < 4; ++c) {
                bf16x8 b = *(const bf16x8*)&Bsl[c * 16 + r][sub * 32 + q * 8];
                acc[c] = __builtin_amdgcn_mfma_f32_16x16x32_bf16(a, b, acc[c], 0, 0, 0);
            }
        }
        __syncthreads();
    }
    const int sel = cg0 >> 9;
    const int within0 = cg0 & 511;
    const float* bias = (sel == 0) ? bk : (sel == 1) ? bv : bq;
    float* C = Kbase + (size_t)sel * 2097152;
#pragma unroll
    for (int c = 0; c < 4; ++c) {
        int col = within0 + c * 16 + r;
        float bb = bias[col];
#pragma unroll
        for (int i = 0; i < 4; ++i) {
            int row = row0 + wave * 16 + q * 4 + i;
            float o = acc[c][i] + bb;
            if (sel != 1) o = gelu_f(o);
            C[(size_t)row * DFF + col] = o;
        }
    }
}

// ---------------------------------------------------------------------------
// MFMA final GEMM: out = attnb @ W_out. A [4096][1024] bf16, Bt [256][1024].
// ---------------------------------------------------------------------------
__global__ __launch_bounds__(256) void mfma_gemm_final(
    const unsigned short* __restrict__ A, const unsigned short* __restrict__ Bt,
    float* __restrict__ out)
{
    const int K = 1024;
    __shared__ unsigned short Asl[64][72];
    __shared__ unsigned short Bsl[64][72];
    const int tid = threadIdx.x;
    const int wave = tid >> 6, lane = tid & 63;
    const int q = lane >> 4, r = lane & 15;
    const int row0 = blockIdx.y * 64, cg0 = blockIdx.x * 64;

    floatx4 acc[4] = {};
    for (int kk = 0; kk < K; kk += 64) {
#pragma unroll
        for (int i = 0; i < 2; ++i) {
            int lin = tid * 2 + i;
            int rr = lin >> 3, kc = (lin & 7) * 8;
            *(float4*)&Asl[rr][kc] = *(const float4*)(A + (size_t)(row0 + rr) * K + kk + kc);
            *(float4*)&Bsl[rr][kc] = *(const float4*)(Bt + (size_t)(cg0 + rr) * K + kk + kc);
        }
        __syncthreads();
#pragma unroll
        for (int sub = 0; sub < 2; ++sub) {
            bf16x8 a = *(const bf16x8*)&Asl[wave * 16 + r][sub * 32 + q * 8];
#pragma unroll
            for (int c = 0; c < 4; ++c) {
                bf16x8 b = *(const bf16x8*)&Bsl[c * 16 + r][sub * 32 + q * 8];
                acc[c] = __builtin_amdgcn_mfma_f32_16x16x32_bf16(a, b, acc[c], 0, 0, 0);
            }
        }
        __syncthreads();
    }
#pragma unroll
    for (int c = 0; c < 4; ++c) {
        int col = cg0 + c * 16 + r;
#pragma unroll
        for (int i = 0; i < 4; ++i) {
            int row = row0 + wave * 16 + q * 4 + i;
            out[(size_t)row * DD + col] = acc[c][i];
        }
    }
}

// ---------------------------------------------------------------------------
// Lsum[seg][d] = sum over masked batch rows of local[n][d]. Grid (8 seg, 4 z).
// ---------------------------------------------------------------------------
__global__ __launch_bounds__(256) void lsum_kernel(
    const float* __restrict__ local, const int* __restrict__ listb_m,
    const int* __restrict__ cntb_m, float* __restrict__ Lsum)
{
    const int seg = blockIdx.x, z = blockIdx.y;
    const int tid = threadIdx.x;
    int c = min(cntb_m[seg], CAP_B);
    int chunk = (c + 3) / 4;
    int r0 = z * chunk, r1 = min(c, r0 + chunk);
    float acc = 0.0f;
    for (int g = r0; g < r1; ++g) {
        int n = listb_m[seg * CAP_B + g];
        acc += local[(size_t)n * DD + tid];
    }
    atomicAdd(&Lsum[seg * DD + tid], acc);
}

// Bsum[seg][j] = sum_k Lsum[seg][k] * W_bias[k][j]. Grid (8 seg, 8 ksplit).
__global__ __launch_bounds__(256) void bsum_kernel(
    const float* __restrict__ Lsum, const float* __restrict__ W_bias,
    float* __restrict__ Bsum)
{
    const int seg = blockIdx.x, kz = blockIdx.y;
    const int tid = threadIdx.x;
    float4 acc = make_float4(0, 0, 0, 0);
    for (int k = kz * 32; k < kz * 32 + 32; ++k) {
        float l = Lsum[seg * DD + k];
        float4 w = *(const float4*)(W_bias + (size_t)k * 1024 + tid * 4);
        acc.x += l * w.x; acc.y += l * w.y; acc.z += l * w.z; acc.w += l * w.w;
    }
    float* o = Bsum + (size_t)seg * 1024 + tid * 4;
    atomicAdd(o + 0, acc.x);
    atomicAdd(o + 1, acc.y);
    atomicAdd(o + 2, acc.z);
    atomicAdd(o + 3, acc.w);
}

// ---------------------------------------------------------------------------
// Segment outer-product SUM from list. Grid (nseg, 8 h, nz).
// ---------------------------------------------------------------------------
__global__ __launch_bounds__(256) void seg_outer_list_kernel(
    const float* __restrict__ Kmat, const float* __restrict__ Vmat,
    const int* __restrict__ list, const int* __restrict__ cnts, int cap,
    float* __restrict__ ST, int nz)
{
    const int seg = blockIdx.x, h = blockIdx.y, z = blockIdx.z;
    __shared__ float Ks[8][64];
    __shared__ float Vs[8][64];
    const int tid = threadIdx.x;
    const int ty = tid >> 4, tx = tid & 15;
    const int mm = tid >> 6, kc = tid & 63;

    int c = min(cnts[seg], cap);
    int chunk = (c + nz - 1) / nz;
    int r0 = z * chunk, r1 = min(c, r0 + chunk);

    float acc[4][4] = {};
    for (int g = r0; g < r1; g += 8) {
        int m = min(8, r1 - g);
        if (mm < m) {
            int nn = list[seg * cap + g + mm];
            Ks[mm][kc] = Kmat[(size_t)nn * DFF + h * DHH + kc];
            Vs[mm][kc] = Vmat[(size_t)nn * DFF + h * DHH + kc];
        }
        if (mm + 4 < m) {
            int nn = list[seg * cap + g + mm + 4];
            Ks[mm + 4][kc] = Kmat[(size_t)nn * DFF + h * DHH + kc];
            Vs[mm + 4][kc] = Vmat[(size_t)nn * DFF + h * DHH + kc];
        }
        __syncthreads();
        for (int qq = 0; qq < m; ++qq) {
            float4 kv = *(const float4*)&Ks[qq][ty * 4];
            float4 vv = *(const float4*)&Vs[qq][tx * 4];
            float ka[4] = {kv.x, kv.y, kv.z, kv.w};
            float vb[4] = {vv.x, vv.y, vv.z, vv.w};
#pragma unroll
            for (int i = 0; i < 4; ++i)
#pragma unroll
                for (int j = 0; j < 4; ++j)
                    acc[i][j] += ka[i] * vb[j];
        }
        __syncthreads();
    }

    float* outp = ST + (((size_t)seg * HH + h) << 12);
    if (nz == 1) {
#pragma unroll
        for (int j = 0; j < 4; ++j) {
            *(float4*)(outp + (size_t)(tx * 4 + j) * 64 + ty * 4) =
                make_float4(acc[0][j], acc[1][j], acc[2][j], acc[3][j]);
        }
    } else {
#pragma unroll
        for (int j = 0; j < 4; ++j) {
            float* o = outp + (size_t)(tx * 4 + j) * 64 + ty * 4;
            atomicAdd(o + 0, acc[0][j]);
            atomicAdd(o + 1, acc[1][j]);
            atomicAdd(o + 2, acc[2][j]);
            atomicAdd(o + 3, acc[3][j]);
        }
    }
}

// ---------------------------------------------------------------------------
// Einsum from list + scale + fused bias; writes attn as bf16.
// ---------------------------------------------------------------------------
__global__ __launch_bounds__(256) void attn_einsum_list_kernel(
    const float* __restrict__ ST, const int* __restrict__ cnt_m,
    const float* __restrict__ Qmat,
    const int* __restrict__ list_all, const int* __restrict__ cnt_all, int cap,
    const int* __restrict__ batch, const int* __restrict__ cntb_m,
    const float* __restrict__ Bsum, const float* __restrict__ b_bias,
    unsigned short* __restrict__ attnb, int outoff, int nz)
{
    const int seg = blockIdx.x, h = blockIdx.y, z = blockIdx.z;
    __shared__ float Sl[64][68];
    __shared__ float qs[16][68];
    const int tid = threadIdx.x;
    const int v4 = tid & 15, slot = tid >> 4;

    float scaleS = 1.0f / fmaxf((float)cnt_m[seg], 1e-6f);
    const float* Sg = ST + (((size_t)seg * HH + h) << 12);
    for (int e = tid; e < 4096; e += 256)
        Sl[e >> 6][e & 63] = Sg[e] * scaleS;

    int c = min(cnt_all[seg], cap);
    int chunk = (c + nz - 1) / nz;
    int r0 = z * chunk, r1 = min(c, r0 + chunk);
    __syncthreads();

    for (int g = r0; g < r1; g += 16) {
        int nn = (g + slot < r1) ? list_all[seg * cap + g + slot] : -1;
        if (nn >= 0) {
            float4 qv = *(const float4*)(Qmat + (size_t)nn * DFF + h * DHH + v4 * 4);
            *(float4*)&qs[slot][v4 * 4] = qv;
        }
        __syncthreads();
        if (nn >= 0) {
            float a0 = 0, a1 = 0, a2 = 0, a3 = 0;
#pragma unroll
            for (int b = 0; b < 64; ++b) {
                float qb = qs[slot][b];
                float4 s = *(const float4*)&Sl[b][v4 * 4];
                a0 += s.x * qb;
                a1 += s.y * qb;
                a2 += s.z * qb;
                a3 += s.w * qb;
            }
            int col0 = h * 128 + outoff + v4 * 4;
            int bb = batch[nn];
            float cm = (float)cntb_m[bb];
            float inv = 1.0f / fmaxf(cm, 1e-6f);
            float4 bi = *(const float4*)(b_bias + col0);
            float4 bs = *(const float4*)(Bsum + (size_t)bb * 1024 + col0);
            a0 += (bs.x + cm * bi.x) * inv;
            a1 += (bs.y + cm * bi.y) * inv;
            a2 += (bs.z + cm * bi.z) * inv;
            a3 += (bs.w + cm * bi.w) * inv;
            ushort4 o;
            o.x = f2b(a0); o.y = f2b(a1); o.z = f2b(a2); o.w = f2b(a3);
            *(ushort4*)(attnb + (size_t)nn * 1024 + col0) = o;
        }
        __syncthreads();
    }
}

extern "C" void kernel_launch(void* const* d_in, const int* in_sizes, int n_in,
                              void* d_out, int out_size, void* d_ws, size_t ws_size,
                              hipStream_t stream)
{
    const float* local   = (const float*)d_in[0];
    const int*   chain   = (const int*)d_in[1];
    const int*   batch   = (const int*)d_in[2];
    const int*   mask    = (const int*)d_in[3];
    const float* W_key   = (const float*)d_in[4];
    const float* b_key   = (const float*)d_in[5];
    const float* W_value = (const float*)d_in[6];
    const float* b_value = (const float*)d_in[7];
    const float* W_query = (const float*)d_in[8];
    const float* b_query = (const float*)d_in[9];
    const float* W_bias  = (const float*)d_in[10];
    const float* b_bias  = (const float*)d_in[11];
    const float* W_out   = (const float*)d_in[12];
    float* out = (float*)d_out;

    float* ws = (float*)d_ws;
    float* Kmat   = ws + OFF_K;
    float* Qmat   = ws + OFF_Q;
    unsigned short* attnb = (unsigned short*)(ws + OFF_ATTNB);
    float* STc    = ws + OFF_STC;
    float* STb    = ws + OFF_STB;
    float* Lsum   = ws + OFF_LSUM;
    float* Bsum   = ws + OFF_BSUM;
    int*   cnt    = (int*)(ws + OFF_CNT);
    unsigned short* localb = (unsigned short*)(ws + OFF_LOCALB);
    unsigned short* Wqkvt  = (unsigned short*)(ws + OFF_WQKVT);
    unsigned short* Woutt  = (unsigned short*)(ws + OFF_WOUTT);
    int* cntc_m   = cnt + 0;
    int* cntc_all = cnt + 64;
    int* cntb_m   = cnt + 128;
    int* cntb_all = cnt + 136;
    int* lists    = (int*)(ws + OFF_LISTS);
    int* listc_m   = lists;
    int* listc_all = listc_m + 64 * CAP_C;
    int* listb_m   = listc_all + 64 * CAP_C;
    int* listb_all = listb_m + 8 * CAP_B;

    dim3 blk(256);

    hipMemsetAsync(ws + OFF_STB, 0, ZERO_BYTES, stream);

    prep_kernel<<<dim3(1680), blk, 0, stream>>>(
        local, W_key, W_value, W_query, W_out, localb, Wqkvt, Woutt,
        chain, batch, mask, cntc_m, cntc_all, cntb_m, cntb_all,
        listc_m, listc_all, listb_m, listb_all);

    mfma_gemm_qkv<<<dim3(24, 64), blk, 0, stream>>>(
        localb, Wqkvt, b_key, b_value, b_query, Kmat);

    lsum_kernel<<<dim3(8, 4), blk, 0, stream>>>(local, listb_m, cntb_m, Lsum);
    bsum_kernel<<<dim3(8, 8), blk, 0, stream>>>(Lsum, W_bias, Bsum);

    seg_outer_list_kernel<<<dim3(64, 8, 1), blk, 0, stream>>>(
        Kmat, Kmat + OFF_V, listc_m, cntc_m, CAP_C, STc, 1);
    seg_outer_list_kernel<<<dim3(8, 8, 8), blk, 0, stream>>>(
        Kmat, Kmat + OFF_V, listb_m, cntb_m, CAP_B, STb, 8);

    attn_einsum_list_kernel<<<dim3(64, 8, 1), blk, 0, stream>>>(
        STc, cntc_m, Qmat, listc_all, cntc_all, CAP_C,
        batch, cntb_m, Bsum, b_bias, attnb, 0, 1);
    attn_einsum_list_kernel<<<dim3(8, 8, 8), blk, 0, stream>>>(
        STb, cntb_m, Qmat, listb_all, cntb_all, CAP_B,
        batch, cntb_m, Bsum, b_bias, attnb, 64, 8);

    mfma_gemm_final<<<dim3(4, 64), blk, 0, stream>>>(attnb, Woutt, out);
}

// Round 4
// 207.319 us; speedup vs baseline: 2.3869x; 1.2660x over previous
//
#include <hip/hip_runtime.h>
#include <math.h>

#define NN 4096
#define DD 256
#define DFF 512
#define HH 8
#define DHH 64

#define CAP_C 256
#define CAP_B 1024

// ws layout (float-element offsets)
#define OFF_KB     0         /* bf16 K [4096][512] = 1,048,576 floats */
#define OFF_VB     1048576
#define OFF_QB     2097152
#define OFF_ATTNB  3145728   /* bf16 attn [4096][1024] = 2,097,152 floats */
#define OFF_STC    5242880   /* fp32 64*8*4096 */
#define OFF_STB    7340032   /* fp32 8*8*4096; zero span start */
#define OFF_LSUM   7602176
#define OFF_BSUM   7604224
#define OFF_CNT    7612416   /* 256 ints; zero span end at 7612672 */
#define OFF_LOCALB 7612672   /* bf16 local [4096][256] = 524,288 floats */
#define OFF_WQKVT  8136960   /* bf16 Wqkv^T [1536][256] = 196,608 floats */
#define OFF_WOUTT  8333568   /* bf16 Wout^T [256][1024] = 131,072 floats */
#define OFF_LISTS  8464640   /* 49,152 ints */
#define ZERO_BYTES ((OFF_LOCALB - OFF_STB) * 4)

typedef __attribute__((ext_vector_type(8))) short bf16x8;
typedef __attribute__((ext_vector_type(4))) float floatx4;

__device__ __forceinline__ float gelu_f(float x) {
    const float c = 0.7978845608028654f;
    float t = tanhf(c * (x + 0.044715f * x * x * x));
    return 0.5f * x * (1.0f + t);
}

__device__ __forceinline__ unsigned short f2b(float f) {
    union { float f; unsigned int u; } v; v.f = f;
    unsigned int r = (v.u + 0x7FFFu + ((v.u >> 16) & 1u)) >> 16;
    return (unsigned short)r;
}

__device__ __forceinline__ float b2f(unsigned short u) {
    union { unsigned int u; float f; } v; v.u = ((unsigned int)u) << 16;
    return v.f;
}

// ---------------------------------------------------------------------------
// prep: [0,1024) cast local->bf16; [1024,1664) transpose-cast weights;
// [1664,1680) build segment lists.
// ---------------------------------------------------------------------------
__global__ __launch_bounds__(256) void prep_kernel(
    const float* __restrict__ local,
    const float* __restrict__ Wk, const float* __restrict__ Wv,
    const float* __restrict__ Wq, const float* __restrict__ Wout,
    unsigned short* __restrict__ localb, unsigned short* __restrict__ Wqkvt,
    unsigned short* __restrict__ Woutt,
    const int* __restrict__ chain, const int* __restrict__ batch,
    const int* __restrict__ mask,
    int* __restrict__ cntc_m, int* __restrict__ cntc_all,
    int* __restrict__ cntb_m, int* __restrict__ cntb_all,
    int* __restrict__ listc_m, int* __restrict__ listc_all,
    int* __restrict__ listb_m, int* __restrict__ listb_all)
{
    const int bid = blockIdx.x, tid = threadIdx.x;
    if (bid < 1024) {
        int base = bid * 1024 + tid * 4;
        float4 v = *(const float4*)(local + base);
        ushort4 o;
        o.x = f2b(v.x); o.y = f2b(v.y); o.z = f2b(v.z); o.w = f2b(v.w);
        *(ushort4*)(localb + base) = o;
    } else if (bid < 1664) {
        int t = bid - 1024;
        const float* src; unsigned short* dst; int R, C, r0, c0;
        if (t < 384) {
            int m = t >> 7, ti = t & 127;
            src = (m == 0) ? Wk : (m == 1) ? Wv : Wq;
            dst = Wqkvt + (size_t)m * 512 * 256;
            R = 256; C = 512;
            r0 = (ti >> 4) * 32; c0 = (ti & 15) * 32;
        } else {
            int ti = t - 384;
            src = Wout; dst = Woutt;
            R = 1024; C = 256;
            r0 = (ti >> 3) * 32; c0 = (ti & 7) * 32;
        }
        __shared__ float Tl[32][33];
        int ty = tid >> 3, tx = tid & 7;
        float4 v = *(const float4*)(src + (size_t)(r0 + ty) * C + c0 + tx * 4);
        Tl[tx * 4 + 0][ty] = v.x;
        Tl[tx * 4 + 1][ty] = v.y;
        Tl[tx * 4 + 2][ty] = v.z;
        Tl[tx * 4 + 3][ty] = v.w;
        __syncthreads();
        int cy = tid >> 3, rx = tid & 7;
        ushort4 o;
        o.x = f2b(Tl[cy][rx * 4 + 0]);
        o.y = f2b(Tl[cy][rx * 4 + 1]);
        o.z = f2b(Tl[cy][rx * 4 + 2]);
        o.w = f2b(Tl[cy][rx * 4 + 3]);
        *(ushort4*)(dst + (size_t)(c0 + cy) * R + r0 + rx * 4) = o;
    } else {
        int n = (bid - 1664) * 256 + tid;
        int c = chain[n], b = batch[n], m = mask[n];
        int p;
        p = atomicAdd(&cntc_all[c], 1); if (p < CAP_C) listc_all[c * CAP_C + p] = n;
        p = atomicAdd(&cntb_all[b], 1); if (p < CAP_B) listb_all[b * CAP_B + p] = n;
        if (m) {
            p = atomicAdd(&cntc_m[c], 1); if (p < CAP_C) listc_m[c * CAP_C + p] = n;
            p = atomicAdd(&cntb_m[b], 1); if (p < CAP_B) listb_m[b * CAP_B + p] = n;
        }
    }
}

// ---------------------------------------------------------------------------
// QKV GEMM (bf16 MFMA, bf16 out) + lsum rider.
// Grid (25, 64): x<24 -> 64x64 GEMM tile (sel = x/8); x==24 -> lsum blocks
// (seg = y>>3, z = y&7): Lsum[seg][d] += masked local row sums (fp32 path).
// ---------------------------------------------------------------------------
__global__ __launch_bounds__(256) void qkv_plus_kernel(
    const unsigned short* __restrict__ A, const unsigned short* __restrict__ Bt,
    const float* __restrict__ bk, const float* __restrict__ bv,
    const float* __restrict__ bq,
    unsigned short* __restrict__ KVQb,
    const float* __restrict__ local, const int* __restrict__ listb_m,
    const int* __restrict__ cntb_m, float* __restrict__ Lsum)
{
    const int tid = threadIdx.x;
    if (blockIdx.x == 24) {
        const int seg = blockIdx.y >> 3, z = blockIdx.y & 7;
        int c = min(cntb_m[seg], CAP_B);
        int chunk = (c + 7) / 8;
        int r0 = z * chunk, r1 = min(c, r0 + chunk);
        float acc = 0.0f;
        for (int g = r0; g < r1; ++g) {
            int n = listb_m[seg * CAP_B + g];
            acc += local[(size_t)n * DD + tid];
        }
        atomicAdd(&Lsum[seg * DD + tid], acc);
        return;
    }
    const int K = 256;
    __shared__ unsigned short Asl[64][72];
    __shared__ unsigned short Bsl[64][72];
    const int wave = tid >> 6, lane = tid & 63;
    const int q = lane >> 4, r = lane & 15;
    const int row0 = blockIdx.y * 64, cg0 = blockIdx.x * 64;

    floatx4 acc[4] = {};
    for (int kk = 0; kk < K; kk += 64) {
#pragma unroll
        for (int i = 0; i < 2; ++i) {
            int lin = tid * 2 + i;
            int rr = lin >> 3, kc = (lin & 7) * 8;
            *(float4*)&Asl[rr][kc] = *(const float4*)(A + (size_t)(row0 + rr) * K + kk + kc);
            *(float4*)&Bsl[rr][kc] = *(const float4*)(Bt + (size_t)(cg0 + rr) * K + kk + kc);
        }
        __syncthreads();
#pragma unroll
        for (int sub = 0; sub < 2; ++sub) {
            bf16x8 a = *(const bf16x8*)&Asl[wave * 16 + r][sub * 32 + q * 8];
#pragma unroll
            for (int c = 0; c < 4; ++c) {
                bf16x8 b = *(const bf16x8*)&Bsl[c * 16 + r][sub * 32 + q * 8];
                acc[c] = __builtin_amdgcn_mfma_f32_16x16x32_bf16(a, b, acc[c], 0, 0, 0);
            }
        }
        __syncthreads();
    }
    const int sel = cg0 >> 9;
    const int within0 = cg0 & 511;
    const float* bias = (sel == 0) ? bk : (sel == 1) ? bv : bq;
    unsigned short* C = KVQb + (size_t)sel * (NN * DFF);
#pragma unroll
    for (int c = 0; c < 4; ++c) {
        int col = within0 + c * 16 + r;
        float bb = bias[col];
#pragma unroll
        for (int i = 0; i < 4; ++i) {
            int row = row0 + wave * 16 + q * 4 + i;
            float o = acc[c][i] + bb;
            if (sel != 1) o = gelu_f(o);
            C[(size_t)row * DFF + col] = f2b(o);
        }
    }
}

// ---------------------------------------------------------------------------
// mid kernel, flat grid 1088:
//  id <  512: chain seg_outer (seg=id>>3, h=id&7), direct store to STc
//  id < 1024: batch seg_outer (t=id-512: seg=t>>6, h=(t>>3)&7, z=t&7),
//             atomicAdd into zeroed STb
//  id < 1088: bsum (t=id-1024: seg=t>>3, kz=t&7)
// ---------------------------------------------------------------------------
__global__ __launch_bounds__(256) void mid_kernel(
    const unsigned short* __restrict__ Kb, const unsigned short* __restrict__ Vb,
    const int* __restrict__ listc_m, const int* __restrict__ cntc_m,
    float* __restrict__ STc,
    const int* __restrict__ listb_m, const int* __restrict__ cntb_m,
    float* __restrict__ STb,
    const float* __restrict__ Lsum, const float* __restrict__ W_bias,
    float* __restrict__ Bsum)
{
    const int id = blockIdx.x, tid = threadIdx.x;
    if (id >= 1024) {
        int t = id - 1024;
        const int seg = t >> 3, kz = t & 7;
        float4 acc = make_float4(0, 0, 0, 0);
        for (int k = kz * 32; k < kz * 32 + 32; ++k) {
            float l = Lsum[seg * DD + k];
            float4 w = *(const float4*)(W_bias + (size_t)k * 1024 + tid * 4);
            acc.x += l * w.x; acc.y += l * w.y; acc.z += l * w.z; acc.w += l * w.w;
        }
        float* o = Bsum + (size_t)seg * 1024 + tid * 4;
        atomicAdd(o + 0, acc.x);
        atomicAdd(o + 1, acc.y);
        atomicAdd(o + 2, acc.z);
        atomicAdd(o + 3, acc.w);
        return;
    }

    int seg, h, r0, r1, cap;
    const int* list;
    float* ST;
    bool direct;
    if (id < 512) {
        seg = id >> 3; h = id & 7;
        cap = CAP_C; list = listc_m; ST = STc;
        int c = min(cntc_m[seg], CAP_C);
        r0 = 0; r1 = c; direct = true;
    } else {
        int t = id - 512;
        seg = t >> 6; h = (t >> 3) & 7;
        int z = t & 7;
        cap = CAP_B; list = listb_m; ST = STb;
        int c = min(cntb_m[seg], CAP_B);
        int chunk = (c + 7) / 8;
        r0 = z * chunk; r1 = min(c, r0 + chunk); direct = false;
    }

    __shared__ float Ks[8][64];
    __shared__ float Vs[8][64];
    const int ty = tid >> 4, tx = tid & 15;
    const int mm = tid >> 6, kc = tid & 63;

    float acc[4][4] = {};
    for (int g = r0; g < r1; g += 8) {
        int m = min(8, r1 - g);
        if (mm < m) {
            int nn = list[seg * cap + g + mm];
            Ks[mm][kc] = b2f(Kb[(size_t)nn * DFF + h * DHH + kc]);
            Vs[mm][kc] = b2f(Vb[(size_t)nn * DFF + h * DHH + kc]);
        }
        if (mm + 4 < m) {
            int nn = list[seg * cap + g + mm + 4];
            Ks[mm + 4][kc] = b2f(Kb[(size_t)nn * DFF + h * DHH + kc]);
            Vs[mm + 4][kc] = b2f(Vb[(size_t)nn * DFF + h * DHH + kc]);
        }
        __syncthreads();
        for (int qq = 0; qq < m; ++qq) {
            float4 kv = *(const float4*)&Ks[qq][ty * 4];
            float4 vv = *(const float4*)&Vs[qq][tx * 4];
            float ka[4] = {kv.x, kv.y, kv.z, kv.w};
            float vb[4] = {vv.x, vv.y, vv.z, vv.w};
#pragma unroll
            for (int i = 0; i < 4; ++i)
#pragma unroll
                for (int j = 0; j < 4; ++j)
                    acc[i][j] += ka[i] * vb[j];
        }
        __syncthreads();
    }

    float* outp = ST + (((size_t)seg * HH + h) << 12);
    if (direct) {
#pragma unroll
        for (int j = 0; j < 4; ++j) {
            *(float4*)(outp + (size_t)(tx * 4 + j) * 64 + ty * 4) =
                make_float4(acc[0][j], acc[1][j], acc[2][j], acc[3][j]);
        }
    } else {
#pragma unroll
        for (int j = 0; j < 4; ++j) {
            float* o = outp + (size_t)(tx * 4 + j) * 64 + ty * 4;
            atomicAdd(o + 0, acc[0][j]);
            atomicAdd(o + 1, acc[1][j]);
            atomicAdd(o + 2, acc[2][j]);
            atomicAdd(o + 3, acc[3][j]);
        }
    }
}

// ---------------------------------------------------------------------------
// einsum, flat grid 1024: id<512 chain (outoff 0), else batch (outoff 64,
// z-split 8). Reads Qb bf16, writes attnb bf16, fuses S-scale and bias.
// ---------------------------------------------------------------------------
__global__ __launch_bounds__(256) void einsum_kernel(
    const float* __restrict__ STc, const int* __restrict__ cntc_m,
    const int* __restrict__ listc_all, const int* __restrict__ cntc_all,
    const float* __restrict__ STb, const int* __restrict__ cntb_m,
    const int* __restrict__ listb_all, const int* __restrict__ cntb_all,
    const unsigned short* __restrict__ Qb, const int* __restrict__ batch,
    const float* __restrict__ Bsum, const float* __restrict__ b_bias,
    unsigned short* __restrict__ attnb)
{
    const int id = blockIdx.x, tid = threadIdx.x;
    int seg, h, outoff, cap, r0, r1;
    const float* ST;
    const int* list;
    float scaleS;
    if (id < 512) {
        seg = id >> 3; h = id & 7; outoff = 0;
        ST = STc; list = listc_all; cap = CAP_C;
        scaleS = 1.0f / fmaxf((float)cntc_m[seg], 1e-6f);
        r0 = 0; r1 = min(cntc_all[seg], CAP_C);
    } else {
        int t = id - 512;
        seg = t >> 6; h = (t >> 3) & 7;
        int z = t & 7;
        outoff = 64;
        ST = STb; list = listb_all; cap = CAP_B;
        scaleS = 1.0f / fmaxf((float)cntb_m[seg], 1e-6f);
        int c = min(cntb_all[seg], CAP_B);
        int chunk = (c + 7) / 8;
        r0 = z * chunk; r1 = min(c, r0 + chunk);
    }

    __shared__ float Sl[64][68];
    __shared__ float qs[16][68];
    const int v4 = tid & 15, slot = tid >> 4;

    const float* Sg = ST + (((size_t)seg * HH + h) << 12);
    for (int e = tid; e < 4096; e += 256)
        Sl[e >> 6][e & 63] = Sg[e] * scaleS;
    __syncthreads();

    for (int g = r0; g < r1; g += 16) {
        int nn = (g + slot < r1) ? list[seg * cap + g + slot] : -1;
        if (nn >= 0) {
            ushort4 qv = *(const ushort4*)(Qb + (size_t)nn * DFF + h * DHH + v4 * 4);
            qs[slot][v4 * 4 + 0] = b2f(qv.x);
            qs[slot][v4 * 4 + 1] = b2f(qv.y);
            qs[slot][v4 * 4 + 2] = b2f(qv.z);
            qs[slot][v4 * 4 + 3] = b2f(qv.w);
        }
        __syncthreads();
        if (nn >= 0) {
            float a0 = 0, a1 = 0, a2 = 0, a3 = 0;
#pragma unroll
            for (int b = 0; b < 64; ++b) {
                float qb = qs[slot][b];
                float4 s = *(const float4*)&Sl[b][v4 * 4];
                a0 += s.x * qb;
                a1 += s.y * qb;
                a2 += s.z * qb;
                a3 += s.w * qb;
            }
            int col0 = h * 128 + outoff + v4 * 4;
            int bb = batch[nn];
            float cm = (float)cntb_m[bb];
            float inv = 1.0f / fmaxf(cm, 1e-6f);
            float4 bi = *(const float4*)(b_bias + col0);
            float4 bs = *(const float4*)(Bsum + (size_t)bb * 1024 + col0);
            a0 += (bs.x + cm * bi.x) * inv;
            a1 += (bs.y + cm * bi.y) * inv;
            a2 += (bs.z + cm * bi.z) * inv;
            a3 += (bs.w + cm * bi.w) * inv;
            ushort4 o;
            o.x = f2b(a0); o.y = f2b(a1); o.z = f2b(a2); o.w = f2b(a3);
            *(ushort4*)(attnb + (size_t)nn * 1024 + col0) = o;
        }
        __syncthreads();
    }
}

// ---------------------------------------------------------------------------
// Final GEMM: out = attnb @ W_out. 32x64 tile, grid (4,128) = 512 blocks.
// Wave w: rows 16*(w&1).., cols 32*(w>>1)..; 2 acc tiles each.
// ---------------------------------------------------------------------------
__global__ __launch_bounds__(256) void mfma_gemm_final(
    const unsigned short* __restrict__ A, const unsigned short* __restrict__ Bt,
    float* __restrict__ out)
{
    const int K = 1024;
    __shared__ unsigned short Asl[32][72];
    __shared__ unsigned short Bsl[64][72];
    const int tid = threadIdx.x;
    const int wave = tid >> 6, lane = tid & 63;
    const int q = lane >> 4, r = lane & 15;
    const int row0 = blockIdx.y * 32, cg0 = blockIdx.x * 64;
    const int wrow = (wave & 1) * 16, wcol = (wave >> 1) * 32;

    floatx4 acc[2] = {};
    for (int kk = 0; kk < K; kk += 64) {
        {
            int rr = tid >> 3, kc = (tid & 7) * 8;
            *(float4*)&Asl[rr][kc] = *(const float4*)(A + (size_t)(row0 + rr) * K + kk + kc);
        }
#pragma unroll
        for (int i = 0; i < 2; ++i) {
            int lin = tid * 2 + i;
            int rr = lin >> 3, kc = (lin & 7) * 8;
            *(float4*)&Bsl[rr][kc] = *(const float4*)(Bt + (size_t)(cg0 + rr) * K + kk + kc);
        }
        __syncthreads();
#pragma unroll
        for (int sub = 0; sub < 2; ++sub) {
            bf16x8 a = *(const bf16x8*)&Asl[wrow + r][sub * 32 + q * 8];
#pragma unroll
            for (int c = 0; c < 2; ++c) {
                bf16x8 b = *(const bf16x8*)&Bsl[wcol + c * 16 + r][sub * 32 + q * 8];
                acc[c] = __builtin_amdgcn_mfma_f32_16x16x32_bf16(a, b, acc[c], 0, 0, 0);
            }
        }
        __syncthreads();
    }
#pragma unroll
    for (int c = 0; c < 2; ++c) {
        int col = cg0 + wcol + c * 16 + r;
#pragma unroll
        for (int i = 0; i < 4; ++i) {
            int row = row0 + wrow + q * 4 + i;
            out[(size_t)row * DD + col] = acc[c][i];
        }
    }
}

extern "C" void kernel_launch(void* const* d_in, const int* in_sizes, int n_in,
                              void* d_out, int out_size, void* d_ws, size_t ws_size,
                              hipStream_t stream)
{
    const float* local   = (const float*)d_in[0];
    const int*   chain   = (const int*)d_in[1];
    const int*   batch   = (const int*)d_in[2];
    const int*   mask    = (const int*)d_in[3];
    const float* W_key   = (const float*)d_in[4];
    const float* b_key   = (const float*)d_in[5];
    const float* W_value = (const float*)d_in[6];
    const float* b_value = (const float*)d_in[7];
    const float* W_query = (const float*)d_in[8];
    const float* b_query = (const float*)d_in[9];
    const float* W_bias  = (const float*)d_in[10];
    const float* b_bias  = (const float*)d_in[11];
    const float* W_out   = (const float*)d_in[12];
    float* out = (float*)d_out;

    float* ws = (float*)d_ws;
    unsigned short* Kb    = (unsigned short*)(ws + OFF_KB);
    unsigned short* Vb    = (unsigned short*)(ws + OFF_VB);
    unsigned short* Qb    = (unsigned short*)(ws + OFF_QB);
    unsigned short* attnb = (unsigned short*)(ws + OFF_ATTNB);
    float* STc    = ws + OFF_STC;
    float* STb    = ws + OFF_STB;
    float* Lsum   = ws + OFF_LSUM;
    float* Bsum   = ws + OFF_BSUM;
    int*   cnt    = (int*)(ws + OFF_CNT);
    unsigned short* localb = (unsigned short*)(ws + OFF_LOCALB);
    unsigned short* Wqkvt  = (unsigned short*)(ws + OFF_WQKVT);
    unsigned short* Woutt  = (unsigned short*)(ws + OFF_WOUTT);
    int* cntc_m   = cnt + 0;
    int* cntc_all = cnt + 64;
    int* cntb_m   = cnt + 128;
    int* cntb_all = cnt + 136;
    int* lists    = (int*)(ws + OFF_LISTS);
    int* listc_m   = lists;
    int* listc_all = listc_m + 64 * CAP_C;
    int* listb_m   = listc_all + 64 * CAP_C;
    int* listb_all = listb_m + 8 * CAP_B;

    dim3 blk(256);

    hipMemsetAsync(ws + OFF_STB, 0, ZERO_BYTES, stream);

    prep_kernel<<<dim3(1680), blk, 0, stream>>>(
        local, W_key, W_value, W_query, W_out, localb, Wqkvt, Woutt,
        chain, batch, mask, cntc_m, cntc_all, cntb_m, cntb_all,
        listc_m, listc_all, listb_m, listb_all);

    qkv_plus_kernel<<<dim3(25, 64), blk, 0, stream>>>(
        localb, Wqkvt, b_key, b_value, b_query, Kb,
        local, listb_m, cntb_m, Lsum);

    mid_kernel<<<dim3(1088), blk, 0, stream>>>(
        Kb, Vb, listc_m, cntc_m, STc, listb_m, cntb_m, STb,
        Lsum, W_bias, Bsum);

    einsum_kernel<<<dim3(1024), blk, 0, stream>>>(
        STc, cntc_m, listc_all, cntc_all, STb, cntb_m, listb_all, cntb_all,
        Qb, batch, Bsum, b_bias, attnb);

    mfma_gemm_final<<<dim3(4, 128), blk, 0, stream>>>(attnb, Woutt, out);
}

// Round 5
// 173.853 us; speedup vs baseline: 2.8464x; 1.1925x over previous
//
#include <hip/hip_runtime.h>
#include <math.h>

#define NN 4096
#define DD 256
#define DFF 512
#define HH 8
#define DHH 64

#define CAP_C 256
#define CAP_B 1024

// ws layout (float-element offsets)
#define OFF_KB     0         /* bf16 K [4096][512] = 1,048,576 floats */
#define OFF_VB     1048576
#define OFF_QB     2097152
#define OFF_ATTNB  3145728   /* bf16 attn [4096][1024] = 2,097,152 floats */
#define OFF_STC    5242880   /* fp32 64*8*4096, layout [a][b] */
#define OFF_STB    7340032   /* fp32 8*8*4096, layout [a][b]; zero span start */
#define OFF_LSUM   7602176
#define OFF_BSUM   7604224
#define OFF_CNT    7612416   /* 256 ints; zero span end at 7612672 */
#define OFF_LOCALB 7612672   /* bf16 local [4096][256] = 524,288 floats */
#define OFF_WQKVT  8136960   /* bf16 Wqkv^T [1536][256] = 196,608 floats */
#define OFF_WOUTT  8333568   /* bf16 Wout^T [256][1024] = 131,072 floats */
#define OFF_LISTS  8464640   /* 49,152 ints */
#define ZERO_BYTES ((OFF_LOCALB - OFF_STB) * 4)

typedef __attribute__((ext_vector_type(8))) short bf16x8;
typedef __attribute__((ext_vector_type(4))) float floatx4;

__device__ __forceinline__ float gelu_f(float x) {
    const float c = 0.7978845608028654f;
    float t = tanhf(c * (x + 0.044715f * x * x * x));
    return 0.5f * x * (1.0f + t);
}

__device__ __forceinline__ unsigned short f2b(float f) {
    union { float f; unsigned int u; } v; v.f = f;
    unsigned int r = (v.u + 0x7FFFu + ((v.u >> 16) & 1u)) >> 16;
    return (unsigned short)r;
}

__device__ __forceinline__ float b2f(unsigned short u) {
    union { unsigned int u; float f; } v; v.u = ((unsigned int)u) << 16;
    return v.f;
}

// ---------------------------------------------------------------------------
// prep: [0,1024) cast local->bf16; [1024,1664) transpose-cast weights;
// [1664,1680) build segment lists.
// ---------------------------------------------------------------------------
__global__ __launch_bounds__(256) void prep_kernel(
    const float* __restrict__ local,
    const float* __restrict__ Wk, const float* __restrict__ Wv,
    const float* __restrict__ Wq, const float* __restrict__ Wout,
    unsigned short* __restrict__ localb, unsigned short* __restrict__ Wqkvt,
    unsigned short* __restrict__ Woutt,
    const int* __restrict__ chain, const int* __restrict__ batch,
    const int* __restrict__ mask,
    int* __restrict__ cntc_m, int* __restrict__ cntc_all,
    int* __restrict__ cntb_m, int* __restrict__ cntb_all,
    int* __restrict__ listc_m, int* __restrict__ listc_all,
    int* __restrict__ listb_m, int* __restrict__ listb_all)
{
    const int bid = blockIdx.x, tid = threadIdx.x;
    if (bid < 1024) {
        int base = bid * 1024 + tid * 4;
        float4 v = *(const float4*)(local + base);
        ushort4 o;
        o.x = f2b(v.x); o.y = f2b(v.y); o.z = f2b(v.z); o.w = f2b(v.w);
        *(ushort4*)(localb + base) = o;
    } else if (bid < 1664) {
        int t = bid - 1024;
        const float* src; unsigned short* dst; int R, C, r0, c0;
        if (t < 384) {
            int m = t >> 7, ti = t & 127;
            src = (m == 0) ? Wk : (m == 1) ? Wv : Wq;
            dst = Wqkvt + (size_t)m * 512 * 256;
            R = 256; C = 512;
            r0 = (ti >> 4) * 32; c0 = (ti & 15) * 32;
        } else {
            int ti = t - 384;
            src = Wout; dst = Woutt;
            R = 1024; C = 256;
            r0 = (ti >> 3) * 32; c0 = (ti & 7) * 32;
        }
        __shared__ float Tl[32][33];
        int ty = tid >> 3, tx = tid & 7;
        float4 v = *(const float4*)(src + (size_t)(r0 + ty) * C + c0 + tx * 4);
        Tl[tx * 4 + 0][ty] = v.x;
        Tl[tx * 4 + 1][ty] = v.y;
        Tl[tx * 4 + 2][ty] = v.z;
        Tl[tx * 4 + 3][ty] = v.w;
        __syncthreads();
        int cy = tid >> 3, rx = tid & 7;
        ushort4 o;
        o.x = f2b(Tl[cy][rx * 4 + 0]);
        o.y = f2b(Tl[cy][rx * 4 + 1]);
        o.z = f2b(Tl[cy][rx * 4 + 2]);
        o.w = f2b(Tl[cy][rx * 4 + 3]);
        *(ushort4*)(dst + (size_t)(c0 + cy) * R + r0 + rx * 4) = o;
    } else {
        int n = (bid - 1664) * 256 + tid;
        int c = chain[n], b = batch[n], m = mask[n];
        int p;
        p = atomicAdd(&cntc_all[c], 1); if (p < CAP_C) listc_all[c * CAP_C + p] = n;
        p = atomicAdd(&cntb_all[b], 1); if (p < CAP_B) listb_all[b * CAP_B + p] = n;
        if (m) {
            p = atomicAdd(&cntc_m[c], 1); if (p < CAP_C) listc_m[c * CAP_C + p] = n;
            p = atomicAdd(&cntb_m[b], 1); if (p < CAP_B) listb_m[b * CAP_B + p] = n;
        }
    }
}

// ---------------------------------------------------------------------------
// QKV GEMM (bf16 MFMA, bf16 out) + lsum rider. Grid (25, 64).
// ---------------------------------------------------------------------------
__global__ __launch_bounds__(256) void qkv_plus_kernel(
    const unsigned short* __restrict__ A, const unsigned short* __restrict__ Bt,
    const float* __restrict__ bk, const float* __restrict__ bv,
    const float* __restrict__ bq,
    unsigned short* __restrict__ KVQb,
    const float* __restrict__ local, const int* __restrict__ listb_m,
    const int* __restrict__ cntb_m, float* __restrict__ Lsum)
{
    const int tid = threadIdx.x;
    if (blockIdx.x == 24) {
        const int seg = blockIdx.y >> 3, z = blockIdx.y & 7;
        int c = min(cntb_m[seg], CAP_B);
        int chunk = (c + 7) / 8;
        int r0 = z * chunk, r1 = min(c, r0 + chunk);
        float acc = 0.0f;
        for (int g = r0; g < r1; ++g) {
            int n = listb_m[seg * CAP_B + g];
            acc += local[(size_t)n * DD + tid];
        }
        atomicAdd(&Lsum[seg * DD + tid], acc);
        return;
    }
    const int K = 256;
    __shared__ unsigned short Asl[64][72];
    __shared__ unsigned short Bsl[64][72];
    const int wave = tid >> 6, lane = tid & 63;
    const int q = lane >> 4, r = lane & 15;
    const int row0 = blockIdx.y * 64, cg0 = blockIdx.x * 64;

    floatx4 acc[4] = {};
    for (int kk = 0; kk < K; kk += 64) {
#pragma unroll
        for (int i = 0; i < 2; ++i) {
            int lin = tid * 2 + i;
            int rr = lin >> 3, kc = (lin & 7) * 8;
            *(float4*)&Asl[rr][kc] = *(const float4*)(A + (size_t)(row0 + rr) * K + kk + kc);
            *(float4*)&Bsl[rr][kc] = *(const float4*)(Bt + (size_t)(cg0 + rr) * K + kk + kc);
        }
        __syncthreads();
#pragma unroll
        for (int sub = 0; sub < 2; ++sub) {
            bf16x8 a = *(const bf16x8*)&Asl[wave * 16 + r][sub * 32 + q * 8];
#pragma unroll
            for (int c = 0; c < 4; ++c) {
                bf16x8 b = *(const bf16x8*)&Bsl[c * 16 + r][sub * 32 + q * 8];
                acc[c] = __builtin_amdgcn_mfma_f32_16x16x32_bf16(a, b, acc[c], 0, 0, 0);
            }
        }
        __syncthreads();
    }
    const int sel = cg0 >> 9;
    const int within0 = cg0 & 511;
    const float* bias = (sel == 0) ? bk : (sel == 1) ? bv : bq;
    unsigned short* C = KVQb + (size_t)sel * (NN * DFF);
#pragma unroll
    for (int c = 0; c < 4; ++c) {
        int col = within0 + c * 16 + r;
        float bb = bias[col];
#pragma unroll
        for (int i = 0; i < 4; ++i) {
            int row = row0 + wave * 16 + q * 4 + i;
            float o = acc[c][i] + bb;
            if (sel != 1) o = gelu_f(o);
            C[(size_t)row * DFF + col] = f2b(o);
        }
    }
}

// ---------------------------------------------------------------------------
// mid kernel (MFMA seg-outer + bsum rider), flat grid 1088:
//  id <  512: chain (seg=id>>3, h=id&7), direct store, ST layout [a][b]
//  id < 1024: batch z-split 8, atomicAdd into zeroed STb [a][b]
//  id < 1088: bsum
// S[a][b] = sum_n k[n,h,a]*v[n,h,b] via mfma: A=K^T tile (m=a,k=n),
// B=V^T tile (col=b,k=n); K/V staged transposed, zero-padded, 32-n K-tiles.
// ---------------------------------------------------------------------------
__global__ __launch_bounds__(256) void mid_kernel(
    const unsigned short* __restrict__ Kb, const unsigned short* __restrict__ Vb,
    const int* __restrict__ listc_m, const int* __restrict__ cntc_m,
    float* __restrict__ STc,
    const int* __restrict__ listb_m, const int* __restrict__ cntb_m,
    float* __restrict__ STb,
    const float* __restrict__ Lsum, const float* __restrict__ W_bias,
    float* __restrict__ Bsum)
{
    const int id = blockIdx.x, tid = threadIdx.x;
    if (id >= 1024) {
        int t = id - 1024;
        const int seg = t >> 3, kz = t & 7;
        float4 acc = make_float4(0, 0, 0, 0);
        for (int k = kz * 32; k < kz * 32 + 32; ++k) {
            float l = Lsum[seg * DD + k];
            float4 w = *(const float4*)(W_bias + (size_t)k * 1024 + tid * 4);
            acc.x += l * w.x; acc.y += l * w.y; acc.z += l * w.z; acc.w += l * w.w;
        }
        float* o = Bsum + (size_t)seg * 1024 + tid * 4;
        atomicAdd(o + 0, acc.x);
        atomicAdd(o + 1, acc.y);
        atomicAdd(o + 2, acc.z);
        atomicAdd(o + 3, acc.w);
        return;
    }

    int seg, h, r0, r1, cap;
    const int* list;
    float* ST;
    bool direct;
    if (id < 512) {
        seg = id >> 3; h = id & 7;
        cap = CAP_C; list = listc_m; ST = STc;
        int c = min(cntc_m[seg], CAP_C);
        r0 = 0; r1 = c; direct = true;
    } else {
        int t = id - 512;
        seg = t >> 6; h = (t >> 3) & 7;
        int z = t & 7;
        cap = CAP_B; list = listb_m; ST = STb;
        int c = min(cntb_m[seg], CAP_B);
        int chunk = (c + 7) / 8;
        r0 = z * chunk; r1 = min(c, r0 + chunk); direct = false;
    }

    __shared__ unsigned short Ktl[64][36];
    __shared__ unsigned short Vtl[64][36];
    const int wave = tid >> 6, lane = tid & 63;
    const int la = lane & 15, kq = lane >> 4;

    floatx4 acc[4] = {};
    for (int g = r0; g < r1; g += 32) {
#pragma unroll
        for (int it = 0; it < 2; ++it) {
            int item = tid + it * 256;
            int nl = item & 31, aq = item >> 5;   // aq in [0,16)
            int gg = g + nl;
            ushort4 kz4 = make_ushort4(0, 0, 0, 0);
            ushort4 vz4 = make_ushort4(0, 0, 0, 0);
            if (gg < r1) {
                int nn = list[seg * cap + gg];
                kz4 = *(const ushort4*)(Kb + (size_t)nn * DFF + h * DHH + aq * 4);
                vz4 = *(const ushort4*)(Vb + (size_t)nn * DFF + h * DHH + aq * 4);
            }
            Ktl[aq * 4 + 0][nl] = kz4.x;
            Ktl[aq * 4 + 1][nl] = kz4.y;
            Ktl[aq * 4 + 2][nl] = kz4.z;
            Ktl[aq * 4 + 3][nl] = kz4.w;
            Vtl[aq * 4 + 0][nl] = vz4.x;
            Vtl[aq * 4 + 1][nl] = vz4.y;
            Vtl[aq * 4 + 2][nl] = vz4.z;
            Vtl[aq * 4 + 3][nl] = vz4.w;
        }
        __syncthreads();
        bf16x8 a = *(const bf16x8*)&Ktl[wave * 16 + la][kq * 8];
#pragma unroll
        for (int bt = 0; bt < 4; ++bt) {
            bf16x8 b = *(const bf16x8*)&Vtl[bt * 16 + la][kq * 8];
            acc[bt] = __builtin_amdgcn_mfma_f32_16x16x32_bf16(a, b, acc[bt], 0, 0, 0);
        }
        __syncthreads();
    }

    float* outp = ST + (((size_t)seg * HH + h) << 12);
#pragma unroll
    for (int bt = 0; bt < 4; ++bt) {
#pragma unroll
        for (int rg = 0; rg < 4; ++rg) {
            int aa = wave * 16 + kq * 4 + rg;
            int bb = bt * 16 + la;
            if (direct) outp[aa * 64 + bb] = acc[bt][rg];
            else atomicAdd(&outp[aa * 64 + bb], acc[bt][rg]);
        }
    }
}

// ---------------------------------------------------------------------------
// einsum (MFMA), flat grid 1024: id<512 chain (outoff 0), else batch
// (outoff 64, z=8). out[n,a] = sum_b S[a][b]*scale * q[n,b] + biasTable.
// A = gathered q rows; B = S staged bf16 [a][b]; output reordered via LDS.
// ---------------------------------------------------------------------------
__global__ __launch_bounds__(256) void einsum_kernel(
    const float* __restrict__ STc, const int* __restrict__ cntc_m,
    const int* __restrict__ listc_all, const int* __restrict__ cntc_all,
    const float* __restrict__ STb, const int* __restrict__ cntb_m,
    const int* __restrict__ listb_all, const int* __restrict__ cntb_all,
    const unsigned short* __restrict__ Qb, const int* __restrict__ batch,
    const float* __restrict__ Bsum, const float* __restrict__ b_bias,
    unsigned short* __restrict__ attnb)
{
    const int id = blockIdx.x, tid = threadIdx.x;
    int seg, h, outoff, cap, r0, r1;
    const float* ST;
    const int* list;
    float scaleS;
    if (id < 512) {
        seg = id >> 3; h = id & 7; outoff = 0;
        ST = STc; list = listc_all; cap = CAP_C;
        scaleS = 1.0f / fmaxf((float)cntc_m[seg], 1e-6f);
        r0 = 0; r1 = min(cntc_all[seg], CAP_C);
    } else {
        int t = id - 512;
        seg = t >> 6; h = (t >> 3) & 7;
        int z = t & 7;
        outoff = 64;
        ST = STb; list = listb_all; cap = CAP_B;
        scaleS = 1.0f / fmaxf((float)cntb_m[seg], 1e-6f);
        int c = min(cntb_all[seg], CAP_B);
        int chunk = (c + 7) / 8;
        r0 = z * chunk; r1 = min(c, r0 + chunk);
    }

    __shared__ unsigned short Sbl[64][72];   // [a][b], scaled bf16
    __shared__ unsigned short Qsl[64][72];   // q rows, reused as out tile
    __shared__ float Bf[8][64];              // bias table slice
    __shared__ int nrow[64];
    __shared__ int nbb[64];

    const int wave = tid >> 6, lane = tid & 63;
    const int la = lane & 15, kq = lane >> 4;
    const int colbase = h * 128 + outoff;

    const float* Sg = ST + (((size_t)seg * HH + h) << 12);
#pragma unroll
    for (int i = 0; i < 4; ++i) {
        int e = tid + i * 256;               // float4 group index, 1024 total
        float4 v = *(const float4*)(Sg + e * 4);
        int a = e >> 4, b = (e & 15) * 4;
        ushort4 o;
        o.x = f2b(v.x * scaleS); o.y = f2b(v.y * scaleS);
        o.z = f2b(v.z * scaleS); o.w = f2b(v.w * scaleS);
        *(ushort4*)&Sbl[a][b] = o;
    }
#pragma unroll
    for (int e = tid; e < 512; e += 256) {
        int bbq = e >> 6, j = e & 63;
        float cm = (float)cntb_m[bbq];
        float inv = 1.0f / fmaxf(cm, 1e-6f);
        int col = colbase + j;
        Bf[bbq][j] = (Bsum[(size_t)bbq * 1024 + col] + cm * b_bias[col]) * inv;
    }
    __syncthreads();

    for (int g = r0; g < r1; g += 64) {
        if (tid < 64) {
            int gg = g + tid;
            int n = (gg < r1) ? list[seg * cap + gg] : -1;
            nrow[tid] = n;
            nbb[tid] = (n >= 0) ? batch[n] : 0;
        }
        __syncthreads();
        {
            int row = tid & 63, pr = tid >> 6;
            int n = nrow[row];
            if (n >= 0) {
#pragma unroll
                for (int it = 0; it < 2; ++it) {
                    int off = (pr + it * 4) * 8;
                    *(float4*)&Qsl[row][off] =
                        *(const float4*)(Qb + (size_t)n * DFF + h * DHH + off);
                }
            }
        }
        __syncthreads();

        floatx4 acc[4] = {};
#pragma unroll
        for (int ks = 0; ks < 2; ++ks) {
            bf16x8 a = *(const bf16x8*)&Qsl[wave * 16 + la][ks * 32 + kq * 8];
#pragma unroll
            for (int ct = 0; ct < 4; ++ct) {
                bf16x8 b = *(const bf16x8*)&Sbl[ct * 16 + la][ks * 32 + kq * 8];
                acc[ct] = __builtin_amdgcn_mfma_f32_16x16x32_bf16(a, b, acc[ct], 0, 0, 0);
            }
        }
        // write acc+bias into Qsl (each wave writes only its own 16 rows)
#pragma unroll
        for (int ct = 0; ct < 4; ++ct) {
#pragma unroll
            for (int rg = 0; rg < 4; ++rg) {
                int rowl = wave * 16 + kq * 4 + rg;
                float bias = Bf[nbb[rowl]][ct * 16 + la];
                Qsl[rowl][ct * 16 + la] = f2b(acc[ct][rg] + bias);
            }
        }
        __syncthreads();
        {
            int row = tid & 63, pr = tid >> 6;
            int n = nrow[row];
            if (n >= 0) {
#pragma unroll
                for (int it = 0; it < 2; ++it) {
                    int off = (pr + it * 4) * 8;
                    *(float4*)(attnb + (size_t)n * 1024 + colbase + off) =
                        *(const float4*)&Qsl[row][off];
                }
            }
        }
        __syncthreads();
    }
}

// ---------------------------------------------------------------------------
// Final GEMM: out = attnb @ W_out. 32x64 tile, grid (4,128) = 512 blocks.
// ---------------------------------------------------------------------------
__global__ __launch_bounds__(256) void mfma_gemm_final(
    const unsigned short* __restrict__ A, const unsigned short* __restrict__ Bt,
    float* __restrict__ out)
{
    const int K = 1024;
    __shared__ unsigned short Asl[32][72];
    __shared__ unsigned short Bsl[64][72];
    const int tid = threadIdx.x;
    const int wave = tid >> 6, lane = tid & 63;
    const int q = lane >> 4, r = lane & 15;
    const int row0 = blockIdx.y * 32, cg0 = blockIdx.x * 64;
    const int wrow = (wave & 1) * 16, wcol = (wave >> 1) * 32;

    floatx4 acc[2] = {};
    for (int kk = 0; kk < K; kk += 64) {
        {
            int rr = tid >> 3, kc = (tid & 7) * 8;
            *(float4*)&Asl[rr][kc] = *(const float4*)(A + (size_t)(row0 + rr) * K + kk + kc);
        }
#pragma unroll
        for (int i = 0; i < 2; ++i) {
            int lin = tid * 2 + i;
            int rr = lin >> 3, kc = (lin & 7) * 8;
            *(float4*)&Bsl[rr][kc] = *(const float4*)(Bt + (size_t)(cg0 + rr) * K + kk + kc);
        }
        __syncthreads();
#pragma unroll
        for (int sub = 0; sub < 2; ++sub) {
            bf16x8 a = *(const bf16x8*)&Asl[wrow + r][sub * 32 + q * 8];
#pragma unroll
            for (int c = 0; c < 2; ++c) {
                bf16x8 b = *(const bf16x8*)&Bsl[wcol + c * 16 + r][sub * 32 + q * 8];
                acc[c] = __builtin_amdgcn_mfma_f32_16x16x32_bf16(a, b, acc[c], 0, 0, 0);
            }
        }
        __syncthreads();
    }
#pragma unroll
    for (int c = 0; c < 2; ++c) {
        int col = cg0 + wcol + c * 16 + r;
#pragma unroll
        for (int i = 0; i < 4; ++i) {
            int row = row0 + wrow + q * 4 + i;
            out[(size_t)row * DD + col] = acc[c][i];
        }
    }
}

extern "C" void kernel_launch(void* const* d_in, const int* in_sizes, int n_in,
                              void* d_out, int out_size, void* d_ws, size_t ws_size,
                              hipStream_t stream)
{
    const float* local   = (const float*)d_in[0];
    const int*   chain   = (const int*)d_in[1];
    const int*   batch   = (const int*)d_in[2];
    const int*   mask    = (const int*)d_in[3];
    const float* W_key   = (const float*)d_in[4];
    const float* b_key   = (const float*)d_in[5];
    const float* W_value = (const float*)d_in[6];
    const float* b_value = (const float*)d_in[7];
    const float* W_query = (const float*)d_in[8];
    const float* b_query = (const float*)d_in[9];
    const float* W_bias  = (const float*)d_in[10];
    const float* b_bias  = (const float*)d_in[11];
    const float* W_out   = (const float*)d_in[12];
    float* out = (float*)d_out;

    float* ws = (float*)d_ws;
    unsigned short* Kb    = (unsigned short*)(ws + OFF_KB);
    unsigned short* Vb    = (unsigned short*)(ws + OFF_VB);
    unsigned short* Qb    = (unsigned short*)(ws + OFF_QB);
    unsigned short* attnb = (unsigned short*)(ws + OFF_ATTNB);
    float* STc    = ws + OFF_STC;
    float* STb    = ws + OFF_STB;
    float* Lsum   = ws + OFF_LSUM;
    float* Bsum   = ws + OFF_BSUM;
    int*   cnt    = (int*)(ws + OFF_CNT);
    unsigned short* localb = (unsigned short*)(ws + OFF_LOCALB);
    unsigned short* Wqkvt  = (unsigned short*)(ws + OFF_WQKVT);
    unsigned short* Woutt  = (unsigned short*)(ws + OFF_WOUTT);
    int* cntc_m   = cnt + 0;
    int* cntc_all = cnt + 64;
    int* cntb_m   = cnt + 128;
    int* cntb_all = cnt + 136;
    int* lists    = (int*)(ws + OFF_LISTS);
    int* listc_m   = lists;
    int* listc_all = listc_m + 64 * CAP_C;
    int* listb_m   = listc_all + 64 * CAP_C;
    int* listb_all = listb_m + 8 * CAP_B;

    dim3 blk(256);

    hipMemsetAsync(ws + OFF_STB, 0, ZERO_BYTES, stream);

    prep_kernel<<<dim3(1680), blk, 0, stream>>>(
        local, W_key, W_value, W_query, W_out, localb, Wqkvt, Woutt,
        chain, batch, mask, cntc_m, cntc_all, cntb_m, cntb_all,
        listc_m, listc_all, listb_m, listb_all);

    qkv_plus_kernel<<<dim3(25, 64), blk, 0, stream>>>(
        localb, Wqkvt, b_key, b_value, b_query, Kb,
        local, listb_m, cntb_m, Lsum);

    mid_kernel<<<dim3(1088), blk, 0, stream>>>(
        Kb, Vb, listc_m, cntc_m, STc, listb_m, cntb_m, STb,
        Lsum, W_bias, Bsum);

    einsum_kernel<<<dim3(1024), blk, 0, stream>>>(
        STc, cntc_m, listc_all, cntc_all, STb, cntb_m, listb_all, cntb_all,
        Qb, batch, Bsum, b_bias, attnb);

    mfma_gemm_final<<<dim3(4, 128), blk, 0, stream>>>(attnb, Woutt, out);
}

// Round 6
// 158.439 us; speedup vs baseline: 3.1233x; 1.0973x over previous
//
#include <hip/hip_runtime.h>
#include <math.h>

#define NN 4096
#define DD 256
#define DFF 512
#define HH 8
#define DHH 64

#define CAP_C 256
#define CAP_B 1024

// ws layout (float-element offsets)
#define OFF_KB     0         /* bf16 K [4096][512] = 1,048,576 floats */
#define OFF_VB     1048576
#define OFF_QB     2097152
#define OFF_ATTNB  3145728   /* bf16 attn [4096][1024] = 2,097,152 floats */
#define OFF_STC    5242880   /* fp32 64*8*4096, layout [a][b] */
#define OFF_STB    7340032   /* fp32 8*8*4096, layout [a][b]; zero span start */
#define OFF_LSUM   7602176
#define OFF_BSUM   7604224
#define OFF_CNT    7612416   /* 256 ints; zero span end at 7612672 */
#define OFF_LOCALB 7612672   /* bf16 local [4096][256] = 524,288 floats */
#define OFF_WQKVT  8136960   /* bf16 Wqkv^T [1536][256] = 196,608 floats */
#define OFF_WOUTT  8333568   /* bf16 Wout^T [256][1024] = 131,072 floats */
#define OFF_LISTS  8464640   /* 49,152 ints */
#define ZERO_BYTES ((OFF_LOCALB - OFF_STB) * 4)

typedef __attribute__((ext_vector_type(8))) short bf16x8;
typedef __attribute__((ext_vector_type(4))) float floatx4;

__device__ __forceinline__ float gelu_f(float x) {
    const float c = 0.7978845608028654f;
    float t = tanhf(c * (x + 0.044715f * x * x * x));
    return 0.5f * x * (1.0f + t);
}

__device__ __forceinline__ unsigned short f2b(float f) {
    union { float f; unsigned int u; } v; v.f = f;
    unsigned int r = (v.u + 0x7FFFu + ((v.u >> 16) & 1u)) >> 16;
    return (unsigned short)r;
}

__device__ __forceinline__ float b2f(unsigned short u) {
    union { unsigned int u; float f; } v; v.u = ((unsigned int)u) << 16;
    return v.f;
}

// ---------------------------------------------------------------------------
// prep: [0,1024) cast local->bf16; [1024,1664) transpose-cast weights;
// [1664,1680) build segment lists (LDS-aggregated: one global atomic per
// block per segment instead of per element -> kills same-address serialization).
// ---------------------------------------------------------------------------
__global__ __launch_bounds__(256) void prep_kernel(
    const float* __restrict__ local,
    const float* __restrict__ Wk, const float* __restrict__ Wv,
    const float* __restrict__ Wq, const float* __restrict__ Wout,
    unsigned short* __restrict__ localb, unsigned short* __restrict__ Wqkvt,
    unsigned short* __restrict__ Woutt,
    const int* __restrict__ chain, const int* __restrict__ batch,
    const int* __restrict__ mask,
    int* __restrict__ cntc_m, int* __restrict__ cntc_all,
    int* __restrict__ cntb_m, int* __restrict__ cntb_all,
    int* __restrict__ listc_m, int* __restrict__ listc_all,
    int* __restrict__ listb_m, int* __restrict__ listb_all)
{
    const int bid = blockIdx.x, tid = threadIdx.x;
    if (bid < 1024) {
        int base = bid * 1024 + tid * 4;
        float4 v = *(const float4*)(local + base);
        ushort4 o;
        o.x = f2b(v.x); o.y = f2b(v.y); o.z = f2b(v.z); o.w = f2b(v.w);
        *(ushort4*)(localb + base) = o;
    } else if (bid < 1664) {
        int t = bid - 1024;
        const float* src; unsigned short* dst; int R, C, r0, c0;
        if (t < 384) {
            int m = t >> 7, ti = t & 127;
            src = (m == 0) ? Wk : (m == 1) ? Wv : Wq;
            dst = Wqkvt + (size_t)m * 512 * 256;
            R = 256; C = 512;
            r0 = (ti >> 4) * 32; c0 = (ti & 15) * 32;
        } else {
            int ti = t - 384;
            src = Wout; dst = Woutt;
            R = 1024; C = 256;
            r0 = (ti >> 3) * 32; c0 = (ti & 7) * 32;
        }
        __shared__ float Tl[32][33];
        int ty = tid >> 3, tx = tid & 7;
        float4 v = *(const float4*)(src + (size_t)(r0 + ty) * C + c0 + tx * 4);
        Tl[tx * 4 + 0][ty] = v.x;
        Tl[tx * 4 + 1][ty] = v.y;
        Tl[tx * 4 + 2][ty] = v.z;
        Tl[tx * 4 + 3][ty] = v.w;
        __syncthreads();
        int cy = tid >> 3, rx = tid & 7;
        ushort4 o;
        o.x = f2b(Tl[cy][rx * 4 + 0]);
        o.y = f2b(Tl[cy][rx * 4 + 1]);
        o.z = f2b(Tl[cy][rx * 4 + 2]);
        o.w = f2b(Tl[cy][rx * 4 + 3]);
        *(ushort4*)(dst + (size_t)(c0 + cy) * R + r0 + rx * 4) = o;
    } else {
        __shared__ int hc_m[64], hc_all[64], hb_m[8], hb_all[8];
        __shared__ int pc_m[64], pc_all[64], pb_m[8], pb_all[8];
        if (tid < 64) { hc_m[tid] = 0; hc_all[tid] = 0; }
        if (tid < 8)  { hb_m[tid] = 0; hb_all[tid] = 0; }
        __syncthreads();
        int n = (bid - 1664) * 256 + tid;
        int c = chain[n], b = batch[n], m = mask[n];
        int rc_all = atomicAdd(&hc_all[c], 1);
        int rb_all = atomicAdd(&hb_all[b], 1);
        int rc_m = -1, rb_m = -1;
        if (m) {
            rc_m = atomicAdd(&hc_m[c], 1);
            rb_m = atomicAdd(&hb_m[b], 1);
        }
        __syncthreads();
        if (tid < 64) {
            pc_all[tid] = atomicAdd(&cntc_all[tid], hc_all[tid]);
            pc_m[tid]   = atomicAdd(&cntc_m[tid],   hc_m[tid]);
        }
        if (tid < 8) {
            pb_all[tid] = atomicAdd(&cntb_all[tid], hb_all[tid]);
            pb_m[tid]   = atomicAdd(&cntb_m[tid],   hb_m[tid]);
        }
        __syncthreads();
        int ia = pc_all[c] + rc_all;
        if (ia < CAP_C) listc_all[c * CAP_C + ia] = n;
        int ib = pb_all[b] + rb_all;
        if (ib < CAP_B) listb_all[b * CAP_B + ib] = n;
        if (m) {
            int ja = pc_m[c] + rc_m;
            if (ja < CAP_C) listc_m[c * CAP_C + ja] = n;
            int jb = pb_m[b] + rb_m;
            if (jb < CAP_B) listb_m[b * CAP_B + jb] = n;
        }
    }
}

// ---------------------------------------------------------------------------
// QKV GEMM (bf16 MFMA, bf16 out), 128x128 tile (m93 pattern), BK=64,
// 4 waves each owning a 64x64 quadrant (4x4 16x16 frags). Grid (13, 32):
// x<12 -> GEMM col-tile; x==12 -> lsum rider (seg=y>>2, z=y&3).
// ---------------------------------------------------------------------------
__global__ __launch_bounds__(256) void qkv_plus_kernel(
    const unsigned short* __restrict__ A, const unsigned short* __restrict__ Bt,
    const float* __restrict__ bk, const float* __restrict__ bv,
    const float* __restrict__ bq,
    unsigned short* __restrict__ KVQb,
    const float* __restrict__ local, const int* __restrict__ listb_m,
    const int* __restrict__ cntb_m, float* __restrict__ Lsum)
{
    const int tid = threadIdx.x;
    if (blockIdx.x == 12) {
        const int seg = blockIdx.y >> 2, z = blockIdx.y & 3;
        int c = min(cntb_m[seg], CAP_B);
        int chunk = (c + 3) / 4;
        int r0 = z * chunk, r1 = min(c, r0 + chunk);
        float acc = 0.0f;
        for (int g = r0; g < r1; ++g) {
            int n = listb_m[seg * CAP_B + g];
            acc += local[(size_t)n * DD + tid];
        }
        atomicAdd(&Lsum[seg * DD + tid], acc);
        return;
    }
    const int K = 256;
    __shared__ unsigned short Asl[128][72];
    __shared__ unsigned short Bsl[128][72];
    const int wave = tid >> 6, lane = tid & 63;
    const int kq = lane >> 4, la = lane & 15;
    const int row0 = blockIdx.y * 128, cg0 = blockIdx.x * 128;
    const int wrow = (wave & 1) * 64, wcol = (wave >> 1) * 64;

    floatx4 acc[4][4] = {};
    for (int kk = 0; kk < K; kk += 64) {
#pragma unroll
        for (int t = 0; t < 4; ++t) {
            int idx = tid + t * 256;
            int rr = idx >> 3, kc = (idx & 7) * 8;
            *(float4*)&Asl[rr][kc] = *(const float4*)(A + (size_t)(row0 + rr) * K + kk + kc);
            *(float4*)&Bsl[rr][kc] = *(const float4*)(Bt + (size_t)(cg0 + rr) * K + kk + kc);
        }
        __syncthreads();
#pragma unroll
        for (int ks = 0; ks < 2; ++ks) {
            bf16x8 af[4], bf[4];
#pragma unroll
            for (int t = 0; t < 4; ++t) {
                af[t] = *(const bf16x8*)&Asl[wrow + t * 16 + la][ks * 32 + kq * 8];
                bf[t] = *(const bf16x8*)&Bsl[wcol + t * 16 + la][ks * 32 + kq * 8];
            }
#pragma unroll
            for (int at = 0; at < 4; ++at)
#pragma unroll
                for (int ct = 0; ct < 4; ++ct)
                    acc[at][ct] = __builtin_amdgcn_mfma_f32_16x16x32_bf16(
                        af[at], bf[ct], acc[at][ct], 0, 0, 0);
        }
        __syncthreads();
    }
    const int sel = cg0 >> 9;
    const int do_gelu = (sel != 1);
    const float* bias = (sel == 0) ? bk : (sel == 1) ? bv : bq;
    unsigned short* C = KVQb + (size_t)sel * (NN * DFF);
#pragma unroll
    for (int ct = 0; ct < 4; ++ct) {
        int col = cg0 + wcol + ct * 16 + la;
        int colw = col & 511;
        float bb = bias[colw];
#pragma unroll
        for (int at = 0; at < 4; ++at) {
#pragma unroll
            for (int i = 0; i < 4; ++i) {
                int row = row0 + wrow + at * 16 + kq * 4 + i;
                float o = acc[at][ct][i] + bb;
                if (do_gelu) o = gelu_f(o);
                C[(size_t)row * DFF + colw] = f2b(o);
            }
        }
    }
}

// ---------------------------------------------------------------------------
// mid kernel (MFMA seg-outer + bsum rider), flat grid 1088. ST layout [a][b].
// ---------------------------------------------------------------------------
__global__ __launch_bounds__(256) void mid_kernel(
    const unsigned short* __restrict__ Kb, const unsigned short* __restrict__ Vb,
    const int* __restrict__ listc_m, const int* __restrict__ cntc_m,
    float* __restrict__ STc,
    const int* __restrict__ listb_m, const int* __restrict__ cntb_m,
    float* __restrict__ STb,
    const float* __restrict__ Lsum, const float* __restrict__ W_bias,
    float* __restrict__ Bsum)
{
    const int id = blockIdx.x, tid = threadIdx.x;
    if (id >= 1024) {
        int t = id - 1024;
        const int seg = t >> 3, kz = t & 7;
        float4 acc = make_float4(0, 0, 0, 0);
        for (int k = kz * 32; k < kz * 32 + 32; ++k) {
            float l = Lsum[seg * DD + k];
            float4 w = *(const float4*)(W_bias + (size_t)k * 1024 + tid * 4);
            acc.x += l * w.x; acc.y += l * w.y; acc.z += l * w.z; acc.w += l * w.w;
        }
        float* o = Bsum + (size_t)seg * 1024 + tid * 4;
        atomicAdd(o + 0, acc.x);
        atomicAdd(o + 1, acc.y);
        atomicAdd(o + 2, acc.z);
        atomicAdd(o + 3, acc.w);
        return;
    }

    int seg, h, r0, r1, cap;
    const int* list;
    float* ST;
    bool direct;
    if (id < 512) {
        seg = id >> 3; h = id & 7;
        cap = CAP_C; list = listc_m; ST = STc;
        int c = min(cntc_m[seg], CAP_C);
        r0 = 0; r1 = c; direct = true;
    } else {
        int t = id - 512;
        seg = t >> 6; h = (t >> 3) & 7;
        int z = t & 7;
        cap = CAP_B; list = listb_m; ST = STb;
        int c = min(cntb_m[seg], CAP_B);
        int chunk = (c + 7) / 8;
        r0 = z * chunk; r1 = min(c, r0 + chunk); direct = false;
    }

    __shared__ unsigned short Ktl[64][36];
    __shared__ unsigned short Vtl[64][36];
    const int wave = tid >> 6, lane = tid & 63;
    const int la = lane & 15, kq = lane >> 4;

    floatx4 acc[4] = {};
    for (int g = r0; g < r1; g += 32) {
#pragma unroll
        for (int it = 0; it < 2; ++it) {
            int item = tid + it * 256;
            int nl = item & 31, aq = item >> 5;
            int gg = g + nl;
            ushort4 kz4 = make_ushort4(0, 0, 0, 0);
            ushort4 vz4 = make_ushort4(0, 0, 0, 0);
            if (gg < r1) {
                int nn = list[seg * cap + gg];
                kz4 = *(const ushort4*)(Kb + (size_t)nn * DFF + h * DHH + aq * 4);
                vz4 = *(const ushort4*)(Vb + (size_t)nn * DFF + h * DHH + aq * 4);
            }
            Ktl[aq * 4 + 0][nl] = kz4.x;
            Ktl[aq * 4 + 1][nl] = kz4.y;
            Ktl[aq * 4 + 2][nl] = kz4.z;
            Ktl[aq * 4 + 3][nl] = kz4.w;
            Vtl[aq * 4 + 0][nl] = vz4.x;
            Vtl[aq * 4 + 1][nl] = vz4.y;
            Vtl[aq * 4 + 2][nl] = vz4.z;
            Vtl[aq * 4 + 3][nl] = vz4.w;
        }
        __syncthreads();
        bf16x8 a = *(const bf16x8*)&Ktl[wave * 16 + la][kq * 8];
#pragma unroll
        for (int bt = 0; bt < 4; ++bt) {
            bf16x8 b = *(const bf16x8*)&Vtl[bt * 16 + la][kq * 8];
            acc[bt] = __builtin_amdgcn_mfma_f32_16x16x32_bf16(a, b, acc[bt], 0, 0, 0);
        }
        __syncthreads();
    }

    float* outp = ST + (((size_t)seg * HH + h) << 12);
#pragma unroll
    for (int bt = 0; bt < 4; ++bt) {
#pragma unroll
        for (int rg = 0; rg < 4; ++rg) {
            int aa = wave * 16 + kq * 4 + rg;
            int bb = bt * 16 + la;
            if (direct) outp[aa * 64 + bb] = acc[bt][rg];
            else atomicAdd(&outp[aa * 64 + bb], acc[bt][rg]);
        }
    }
}

// ---------------------------------------------------------------------------
// einsum (MFMA), flat grid 1024: id<512 chain (outoff 0), else batch
// (outoff 64, z=8). out[n,a] = sum_b S[a][b]*scale * q[n,b] + biasTable.
// ---------------------------------------------------------------------------
__global__ __launch_bounds__(256) void einsum_kernel(
    const float* __restrict__ STc, const int* __restrict__ cntc_m,
    const int* __restrict__ listc_all, const int* __restrict__ cntc_all,
    const float* __restrict__ STb, const int* __restrict__ cntb_m,
    const int* __restrict__ listb_all, const int* __restrict__ cntb_all,
    const unsigned short* __restrict__ Qb, const int* __restrict__ batch,
    const float* __restrict__ Bsum, const float* __restrict__ b_bias,
    unsigned short* __restrict__ attnb)
{
    const int id = blockIdx.x, tid = threadIdx.x;
    int seg, h, outoff, cap, r0, r1;
    const float* ST;
    const int* list;
    float scaleS;
    if (id < 512) {
        seg = id >> 3; h = id & 7; outoff = 0;
        ST = STc; list = listc_all; cap = CAP_C;
        scaleS = 1.0f / fmaxf((float)cntc_m[seg], 1e-6f);
        r0 = 0; r1 = min(cntc_all[seg], CAP_C);
    } else {
        int t = id - 512;
        seg = t >> 6; h = (t >> 3) & 7;
        int z = t & 7;
        outoff = 64;
        ST = STb; list = listb_all; cap = CAP_B;
        scaleS = 1.0f / fmaxf((float)cntb_m[seg], 1e-6f);
        int c = min(cntb_all[seg], CAP_B);
        int chunk = (c + 7) / 8;
        r0 = z * chunk; r1 = min(c, r0 + chunk);
    }

    __shared__ unsigned short Sbl[64][72];
    __shared__ unsigned short Qsl[64][72];
    __shared__ float Bf[8][64];
    __shared__ int nrow[64];
    __shared__ int nbb[64];

    const int wave = tid >> 6, lane = tid & 63;
    const int la = lane & 15, kq = lane >> 4;
    const int colbase = h * 128 + outoff;

    const float* Sg = ST + (((size_t)seg * HH + h) << 12);
#pragma unroll
    for (int i = 0; i < 4; ++i) {
        int e = tid + i * 256;
        float4 v = *(const float4*)(Sg + e * 4);
        int a = e >> 4, b = (e & 15) * 4;
        ushort4 o;
        o.x = f2b(v.x * scaleS); o.y = f2b(v.y * scaleS);
        o.z = f2b(v.z * scaleS); o.w = f2b(v.w * scaleS);
        *(ushort4*)&Sbl[a][b] = o;
    }
#pragma unroll
    for (int e = tid; e < 512; e += 256) {
        int bbq = e >> 6, j = e & 63;
        float cm = (float)cntb_m[bbq];
        float inv = 1.0f / fmaxf(cm, 1e-6f);
        int col = colbase + j;
        Bf[bbq][j] = (Bsum[(size_t)bbq * 1024 + col] + cm * b_bias[col]) * inv;
    }
    __syncthreads();

    for (int g = r0; g < r1; g += 64) {
        if (tid < 64) {
            int gg = g + tid;
            int n = (gg < r1) ? list[seg * cap + gg] : -1;
            nrow[tid] = n;
            nbb[tid] = (n >= 0) ? batch[n] : 0;
        }
        __syncthreads();
        {
            int row = tid & 63, pr = tid >> 6;
            int n = nrow[row];
            if (n >= 0) {
#pragma unroll
                for (int it = 0; it < 2; ++it) {
                    int off = (pr + it * 4) * 8;
                    *(float4*)&Qsl[row][off] =
                        *(const float4*)(Qb + (size_t)n * DFF + h * DHH + off);
                }
            }
        }
        __syncthreads();

        floatx4 acc[4] = {};
#pragma unroll
        for (int ks = 0; ks < 2; ++ks) {
            bf16x8 a = *(const bf16x8*)&Qsl[wave * 16 + la][ks * 32 + kq * 8];
#pragma unroll
            for (int ct = 0; ct < 4; ++ct) {
                bf16x8 b = *(const bf16x8*)&Sbl[ct * 16 + la][ks * 32 + kq * 8];
                acc[ct] = __builtin_amdgcn_mfma_f32_16x16x32_bf16(a, b, acc[ct], 0, 0, 0);
            }
        }
#pragma unroll
        for (int ct = 0; ct < 4; ++ct) {
#pragma unroll
            for (int rg = 0; rg < 4; ++rg) {
                int rowl = wave * 16 + kq * 4 + rg;
                float bias = Bf[nbb[rowl]][ct * 16 + la];
                Qsl[rowl][ct * 16 + la] = f2b(acc[ct][rg] + bias);
            }
        }
        __syncthreads();
        {
            int row = tid & 63, pr = tid >> 6;
            int n = nrow[row];
            if (n >= 0) {
#pragma unroll
                for (int it = 0; it < 2; ++it) {
                    int off = (pr + it * 4) * 8;
                    *(float4*)(attnb + (size_t)n * 1024 + colbase + off) =
                        *(const float4*)&Qsl[row][off];
                }
            }
        }
        __syncthreads();
    }
}

// ---------------------------------------------------------------------------
// Final GEMM: out = attnb @ W_out. 32x64 tile, BK=128 (8 iters), grid (4,128).
// ---------------------------------------------------------------------------
__global__ __launch_bounds__(256) void mfma_gemm_final(
    const unsigned short* __restrict__ A, const unsigned short* __restrict__ Bt,
    float* __restrict__ out)
{
    const int K = 1024;
    __shared__ unsigned short Asl[32][136];
    __shared__ unsigned short Bsl[64][136];
    const int tid = threadIdx.x;
    const int wave = tid >> 6, lane = tid & 63;
    const int q = lane >> 4, r = lane & 15;
    const int row0 = blockIdx.y * 32, cg0 = blockIdx.x * 64;
    const int wrow = (wave & 1) * 16, wcol = (wave >> 1) * 32;

    floatx4 acc[2] = {};
    for (int kk = 0; kk < K; kk += 128) {
#pragma unroll
        for (int t = 0; t < 2; ++t) {
            int idx = tid + t * 256;
            int rr = idx >> 4, kc = (idx & 15) * 8;
            *(float4*)&Asl[rr][kc] = *(const float4*)(A + (size_t)(row0 + rr) * K + kk + kc);
        }
#pragma unroll
        for (int t = 0; t < 4; ++t) {
            int idx = tid + t * 256;
            int rr = idx >> 4, kc = (idx & 15) * 8;
            *(float4*)&Bsl[rr][kc] = *(const float4*)(Bt + (size_t)(cg0 + rr) * K + kk + kc);
        }
        __syncthreads();
#pragma unroll
        for (int sub = 0; sub < 4; ++sub) {
            bf16x8 a = *(const bf16x8*)&Asl[wrow + r][sub * 32 + q * 8];
#pragma unroll
            for (int c = 0; c < 2; ++c) {
                bf16x8 b = *(const bf16x8*)&Bsl[wcol + c * 16 + r][sub * 32 + q * 8];
                acc[c] = __builtin_amdgcn_mfma_f32_16x16x32_bf16(a, b, acc[c], 0, 0, 0);
            }
        }
        __syncthreads();
    }
#pragma unroll
    for (int c = 0; c < 2; ++c) {
        int col = cg0 + wcol + c * 16 + r;
#pragma unroll
        for (int i = 0; i < 4; ++i) {
            int row = row0 + wrow + q * 4 + i;
            out[(size_t)row * DD + col] = acc[c][i];
        }
    }
}

extern "C" void kernel_launch(void* const* d_in, const int* in_sizes, int n_in,
                              void* d_out, int out_size, void* d_ws, size_t ws_size,
                              hipStream_t stream)
{
    const float* local   = (const float*)d_in[0];
    const int*   chain   = (const int*)d_in[1];
    const int*   batch   = (const int*)d_in[2];
    const int*   mask    = (const int*)d_in[3];
    const float* W_key   = (const float*)d_in[4];
    const float* b_key   = (const float*)d_in[5];
    const float* W_value = (const float*)d_in[6];
    const float* b_value = (const float*)d_in[7];
    const float* W_query = (const float*)d_in[8];
    const float* b_query = (const float*)d_in[9];
    const float* W_bias  = (const float*)d_in[10];
    const float* b_bias  = (const float*)d_in[11];
    const float* W_out   = (const float*)d_in[12];
    float* out = (float*)d_out;

    float* ws = (float*)d_ws;
    unsigned short* Kb    = (unsigned short*)(ws + OFF_KB);
    unsigned short* Vb    = (unsigned short*)(ws + OFF_VB);
    unsigned short* Qb    = (unsigned short*)(ws + OFF_QB);
    unsigned short* attnb = (unsigned short*)(ws + OFF_ATTNB);
    float* STc    = ws + OFF_STC;
    float* STb    = ws + OFF_STB;
    float* Lsum   = ws + OFF_LSUM;
    float* Bsum   = ws + OFF_BSUM;
    int*   cnt    = (int*)(ws + OFF_CNT);
    unsigned short* localb = (unsigned short*)(ws + OFF_LOCALB);
    unsigned short* Wqkvt  = (unsigned short*)(ws + OFF_WQKVT);
    unsigned short* Woutt  = (unsigned short*)(ws + OFF_WOUTT);
    int* cntc_m   = cnt + 0;
    int* cntc_all = cnt + 64;
    int* cntb_m   = cnt + 128;
    int* cntb_all = cnt + 136;
    int* lists    = (int*)(ws + OFF_LISTS);
    int* listc_m   = lists;
    int* listc_all = listc_m + 64 * CAP_C;
    int* listb_m   = listc_all + 64 * CAP_C;
    int* listb_all = listb_m + 8 * CAP_B;

    dim3 blk(256);

    hipMemsetAsync(ws + OFF_STB, 0, ZERO_BYTES, stream);

    prep_kernel<<<dim3(1680), blk, 0, stream>>>(
        local, W_key, W_value, W_query, W_out, localb, Wqkvt, Woutt,
        chain, batch, mask, cntc_m, cntc_all, cntb_m, cntb_all,
        listc_m, listc_all, listb_m, listb_all);

    qkv_plus_kernel<<<dim3(13, 32), blk, 0, stream>>>(
        localb, Wqkvt, b_key, b_value, b_query, Kb,
        local, listb_m, cntb_m, Lsum);

    mid_kernel<<<dim3(1088), blk, 0, stream>>>(
        Kb, Vb, listc_m, cntc_m, STc, listb_m, cntb_m, STb,
        Lsum, W_bias, Bsum);

    einsum_kernel<<<dim3(1024), blk, 0, stream>>>(
        STc, cntc_m, listc_all, cntc_all, STb, cntb_m, listb_all, cntb_all,
        Qb, batch, Bsum, b_bias, attnb);

    mfma_gemm_final<<<dim3(4, 128), blk, 0, stream>>>(attnb, Woutt, out);
}